// Round 8
// baseline (485.555 us; speedup 1.0000x reference)
//
#include <hip/hip_runtime.h>
#include <math.h>

#define NB   8
#define NC   512
#define SP   4096
#define TOT  16777216L
static const double PI_D = 3.14159265358979323846;

typedef short s16x8 __attribute__((ext_vector_type(8)));
typedef float f32x4 __attribute__((ext_vector_type(4)));
typedef unsigned short u16;

// ---------------- ws layout (float units) ----------------
// region A [0,16777216): t16 [0,8.39M); cand [0,8.39M); partials [8.39M,9.97M);
//   Gf [9971712,10102784) (written setup, read conv1, clobbered by X2/idct1);
//   h1pre/lgn [0,8.39M); X2 [8.39M,16.78M)
// region B [16777216,25165824): thi (FULL region); later h1
// region C [25165824,41943040): ctab (setup) then D fp32; later h2
// tail: old-Ak slot [41943040,42205184) now hosts Akfh/Akfl (dead fp32 Ak)
#define OFF_T    0L
#define OFF_CAND 0L                   // u32[2048*4096] candidate slices (32 MB)
#define OFF_CNT  8388608L             // u32[2048] per-block counts
#define OFF_P2   8392704L             // u32[256*4096] hist2 partials
#define OFF_P3   9441280L             // u32[256*2048] hist3 partials
#define OFF_H2R  9965568L             // u32[4096] reduced hist2
#define OFF_H3R  9969664L             // u32[2048] reduced hist3
#define OFF_GF   9971712L             // u16[262144] Gf fragment-major (conv1; dies at idct1)
#define OFF_H1P  0L                   // h1pre bf16 [32][128][4096]; later lgn (same size)
#define OFF_X2   8388608L
#define OFF_THI  16777216L            // thi u16[16.78M] spans ALL of region B
#define OFF_H1   16777216L            // h1 occupies region B AFTER idct2
#define OFF_D    25165824L            // D fp32; ALSO hosts ctab float[2048] during setup only
#define OFF_H2   25165824L
#define OFF_AKFH 41943040L            // u16[262144] Akf hi (old dead fp32-Ak slot)
#define OFF_AKFL 42074112L            // u16[262144] Akf lo
#define OFF_AKH  42205184L
#define OFF_AKL  42336256L
#define OFF_ACT  42467328L
#define OFF_GBF  42468352L
#define OFF_W2A  42599424L            // W2f fragment-major
#define OFF_W3B  42894336L            // W3f fragment-major
#define OFF_HIST 42927104L            // hist1 4096 (u32)
#define OFF_SEL  42937344L            // u32[16]
#define OFF_THR  42937360L            // float[4]
#define OFF_ACH  42937368L            // u16[4096] A64 hi
#define OFF_ACL  42939416L            // u16[4096] A64 lo

__device__ inline u16 bfr(float x) {
    unsigned u = __float_as_uint(x);
    unsigned r = u + 0x7fffu + ((u >> 16) & 1u);
    return (u16)(r >> 16);
}
__device__ inline float bff(u16 h) { return __uint_as_float(((unsigned)h) << 16); }

#define MFMA(a, b, c) __builtin_amdgcn_mfma_f32_16x16x32_bf16((a), (b), (c), 0, 0, 0)

// ---------------- setup kernels ----------------
__global__ void k_ctab(float* __restrict__ ctab) {
    int m = blockIdx.x * 256 + threadIdx.x;
    if (m < 2048) ctab[m] = (float)cos(PI_D * (double)m / 1024.0);
}

__global__ void k_build_mats(const float* __restrict__ ctab,
                             u16* __restrict__ Akh, u16* __restrict__ Akl,
                             u16* __restrict__ Akfh, u16* __restrict__ Akfl,
                             u16* __restrict__ AcT, u16* __restrict__ Ach, u16* __restrict__ Acl) {
    int idx = blockIdx.x * 256 + threadIdx.x;
    if (idx < 512 * 512) {
        int i = idx >> 9, j = idx & 511;
        float c = ctab[(i * (2 * j + 1)) & 2047];
        float f = c * (i == 0 ? 0.04419417382415922f : 0.0625f);
        u16 h = bfr(f);
        u16 l = bfr(f - bff(h));
        Akh[idx] = h;
        Akl[idx] = l;
        // fragment-major copy for cgemm: groups [kc/16][c/32], within: lane*8+q
        long fa = ((long)(i >> 4) * 16 + (j >> 5)) * 512 + ((j >> 3) & 3) * 128 + (i & 15) * 8 + (j & 7);
        Akfh[fa] = h;
        Akfl[fa] = l;
    }
    if (idx < 64 * 64) {
        int i = idx >> 6, j = idx & 63;
        float c = ctab[(8 * i * (2 * j + 1)) & 2047];
        float a = c * (i == 0 ? 0.125f : 0.17677669529663687f);
        u16 ah = bfr(a);
        Ach[idx] = ah;
        Acl[idx] = bfr(a - bff(ah));
        int n = idx >> 6, np = idx & 63;
        float w = ctab[(8 * np * (2 * n + 1)) & 2047];
        AcT[idx] = bfr(w * (np == 0 ? 0.125f : 0.17677669529663687f));
    }
}

__global__ void k_zero(unsigned* __restrict__ p, int n) {
    int i = blockIdx.x * 256 + threadIdx.x;
    if (i < n) p[i] = 0u;
}

// G = W1 x Ak^T via MFMA, output bf16 row-major (reshuffled by k_gf).
__global__ __launch_bounds__(256, 2) void k_gmm(const float* __restrict__ W1,
                                                const u16* __restrict__ Akh, const u16* __restrict__ Akl,
                                                u16* __restrict__ G) {
    __shared__ __align__(16) short Wh[128 * 40];
    __shared__ __align__(16) short Wl[128 * 40];
    __shared__ __align__(16) short Qh[128 * 40];
    __shared__ __align__(16) short Ql[128 * 40];
    const int p0 = blockIdx.y * 128, kc0 = blockIdx.x * 128;
    const int tid = threadIdx.x;
    const int lane = tid & 63, wave = tid >> 6;
    const int fr = lane & 15, qd = lane >> 4;
    const int mq = (wave >> 1) * 64, nq = (wave & 1) * 64;
    f32x4 acc[4][4];
#pragma unroll
    for (int i = 0; i < 4; ++i)
#pragma unroll
        for (int j = 0; j < 4; ++j) acc[i][j] = (f32x4){0.f, 0.f, 0.f, 0.f};
    const float* Pg = W1 + (long)p0 * 512;
    const u16* Qgh = Akh + (long)kc0 * 512;
    const u16* Qgl = Akl + (long)kc0 * 512;
    const int r0 = tid >> 2, q40 = (tid & 3) * 8;
    float4 pa4[2], pb4[2];
    s16x8 qsh[2], qsl[2];
#pragma unroll
    for (int j = 0; j < 2; ++j) {
        int r = r0 + j * 64;
        const float* src = &Pg[(long)r * 512 + q40];
        pa4[j] = *(const float4*)src;
        pb4[j] = *(const float4*)(src + 4);
        qsh[j] = *(const s16x8*)&Qgh[(long)r * 512 + q40];
        qsl[j] = *(const s16x8*)&Qgl[(long)r * 512 + q40];
    }
    for (int ch = 0; ch < 16; ++ch) {
        __syncthreads();
#pragma unroll
        for (int j = 0; j < 2; ++j) {
            int r = r0 + j * 64;
            float f[8] = {pa4[j].x, pa4[j].y, pa4[j].z, pa4[j].w,
                          pb4[j].x, pb4[j].y, pb4[j].z, pb4[j].w};
            s16x8 vh, vl;
#pragma unroll
            for (int q = 0; q < 8; ++q) {
                u16 h = bfr(f[q]);
                vh[q] = (short)h;
                vl[q] = (short)bfr(f[q] - bff(h));
            }
            *(s16x8*)&Wh[r * 40 + q40] = vh;
            *(s16x8*)&Wl[r * 40 + q40] = vl;
            *(s16x8*)&Qh[r * 40 + q40] = qsh[j];
            *(s16x8*)&Ql[r * 40 + q40] = qsl[j];
        }
        __syncthreads();
        if (ch < 15) {
            const int kn = (ch + 1) * 32;
#pragma unroll
            for (int j = 0; j < 2; ++j) {
                int r = r0 + j * 64;
                const float* src = &Pg[(long)r * 512 + kn + q40];
                pa4[j] = *(const float4*)src;
                pb4[j] = *(const float4*)(src + 4);
                qsh[j] = *(const s16x8*)&Qgh[(long)r * 512 + kn + q40];
                qsl[j] = *(const s16x8*)&Qgl[(long)r * 512 + kn + q40];
            }
        }
        s16x8 qfh[4], qfl[4];
#pragma unroll
        for (int j = 0; j < 4; ++j) {
            qfh[j] = *(const s16x8*)&Qh[(nq + 16 * j + fr) * 40 + qd * 8];
            qfl[j] = *(const s16x8*)&Ql[(nq + 16 * j + fr) * 40 + qd * 8];
        }
#pragma unroll
        for (int i = 0; i < 4; ++i) {
            s16x8 wh = *(const s16x8*)&Wh[(mq + 16 * i + fr) * 40 + qd * 8];
            s16x8 wl = *(const s16x8*)&Wl[(mq + 16 * i + fr) * 40 + qd * 8];
#pragma unroll
            for (int j = 0; j < 4; ++j) {
                acc[i][j] = MFMA(wh, qfh[j], acc[i][j]);
                acc[i][j] = MFMA(wh, qfl[j], acc[i][j]);
                acc[i][j] = MFMA(wl, qfh[j], acc[i][j]);
            }
        }
    }
#pragma unroll
    for (int i = 0; i < 4; ++i)
#pragma unroll
        for (int j = 0; j < 4; ++j) {
            int rowb = mq + 16 * i + qd * 4;
            int col = kc0 + nq + 16 * j + fr;
#pragma unroll
            for (int r = 0; r < 4; ++r)
                G[(long)(p0 + rowb + r) * 512 + col] = bfr(acc[i][j][r]);
        }
}

// reshuffle G (row-major) -> Gf (fragment-major): Gf[((br*16+ch)*8+of)*512+lane*8+q]
__global__ void k_gf(const u16* __restrict__ G, u16* __restrict__ Gf) {
    int fidx = blockIdx.x * 256 + threadIdx.x;   // 32768 units of 16B
    int lane = fidx & 63;
    int of = (fidx >> 6) & 7;
    int ch = (fidx >> 9) & 15;
    int br = fidx >> 13;
    int fr = lane & 15, qd = lane >> 4;
    s16x8 v = *(const s16x8*)&G[((long)(br * 128 + of * 16 + fr)) * 512 + ch * 32 + qd * 8];
    *(s16x8*)&Gf[(long)fidx * 8] = v;
}

// W2f fragment-major: [br][ch=36][of=8][lane=64][8]; W3f: [br][ch=4][of=8][lane][8]
__global__ void k_wprep(const float* __restrict__ W2, const float* __restrict__ W3,
                        u16* __restrict__ W2f, u16* __restrict__ W3f) {
    int idx = blockIdx.x * 256 + threadIdx.x;
    if (idx < 589824) {
        int q = idx & 7;
        int lane = (idx >> 3) & 63;
        int of = (idx >> 9) & 7;
        int rest = idx >> 12;
        int ch = rest % 36;
        int br = rest / 36;
        int o = of * 16 + (lane & 15);
        int t = ch >> 2;
        int ci = (ch & 3) * 32 + (lane >> 4) * 8 + q;
        W2f[idx] = bfr(W2[(((long)br * 128 + o) * 128 + ci) * 9 + t]);
    }
    if (idx < 65536) {
        int q = idx & 7;
        int lane = (idx >> 3) & 63;
        int of = (idx >> 9) & 7;
        int ch = (idx >> 12) & 3;
        int br = idx >> 14;
        int o = of * 16 + (lane & 15);
        int k = ch * 32 + (lane >> 4) * 8 + q;
        W3f[idx] = bfr(W3[((long)br * 128 + o) * 128 + k]);
    }
}

// ---------------- forward 2D DCT tile via MFMA ----------------
__global__ __launch_bounds__(256, 3) void k_tile_fwd(const float* __restrict__ in,
                                                     u16* __restrict__ out16,
                                                     const u16* __restrict__ Ach,
                                                     const u16* __restrict__ Acl) {
    __shared__ __align__(16) short Xb[64 * 72];
    __shared__ __align__(16) short Ah[64 * 72];
    __shared__ __align__(16) short Al[64 * 72];
    __shared__ __align__(16) short Uh[64 * 72];
    __shared__ __align__(16) short Ul[64 * 72];
    const int tid = threadIdx.x;
    const long tile = blockIdx.x;
    const float* __restrict__ src = in + tile * 4096;
    u16* __restrict__ dst = out16 + tile * 4096;
    {
        const int r = tid >> 2, q16 = (tid & 3) * 16;
        const float* s = &src[r * 64 + q16];
        float4 f0 = *(const float4*)s;
        float4 f1 = *(const float4*)(s + 4);
        float4 f2 = *(const float4*)(s + 8);
        float4 f3 = *(const float4*)(s + 12);
        s16x8 v0, v1;
        v0[0] = (short)bfr(f0.x); v0[1] = (short)bfr(f0.y);
        v0[2] = (short)bfr(f0.z); v0[3] = (short)bfr(f0.w);
        v0[4] = (short)bfr(f1.x); v0[5] = (short)bfr(f1.y);
        v0[6] = (short)bfr(f1.z); v0[7] = (short)bfr(f1.w);
        v1[0] = (short)bfr(f2.x); v1[1] = (short)bfr(f2.y);
        v1[2] = (short)bfr(f2.z); v1[3] = (short)bfr(f2.w);
        v1[4] = (short)bfr(f3.x); v1[5] = (short)bfr(f3.y);
        v1[6] = (short)bfr(f3.z); v1[7] = (short)bfr(f3.w);
        *(s16x8*)&Xb[r * 72 + q16] = v0;
        *(s16x8*)&Xb[r * 72 + q16 + 8] = v1;
        *(s16x8*)&Ah[r * 72 + q16] = *(const s16x8*)&Ach[r * 64 + q16];
        *(s16x8*)&Ah[r * 72 + q16 + 8] = *(const s16x8*)&Ach[r * 64 + q16 + 8];
        *(s16x8*)&Al[r * 72 + q16] = *(const s16x8*)&Acl[r * 64 + q16];
        *(s16x8*)&Al[r * 72 + q16 + 8] = *(const s16x8*)&Acl[r * 64 + q16 + 8];
    }
    __syncthreads();
    const int lane = tid & 63, wave = tid >> 6;
    const int fr = lane & 15, qd = lane >> 4;
    const int mq = (wave >> 1) * 32, nq = (wave & 1) * 32;
    f32x4 a1[2][2];
#pragma unroll
    for (int i = 0; i < 2; ++i)
#pragma unroll
        for (int j = 0; j < 2; ++j) a1[i][j] = (f32x4){0.f, 0.f, 0.f, 0.f};
#pragma unroll
    for (int ks = 0; ks < 2; ++ks) {
        const int k0 = ks * 32 + qd * 8;
        s16x8 xp[2];
#pragma unroll
        for (int i = 0; i < 2; ++i) xp[i] = *(const s16x8*)&Xb[(mq + 16 * i + fr) * 72 + k0];
#pragma unroll
        for (int j = 0; j < 2; ++j) {
            s16x8 qh = *(const s16x8*)&Ah[(nq + 16 * j + fr) * 72 + k0];
            s16x8 ql = *(const s16x8*)&Al[(nq + 16 * j + fr) * 72 + k0];
#pragma unroll
            for (int i = 0; i < 2; ++i) {
                a1[i][j] = MFMA(xp[i], qh, a1[i][j]);
                a1[i][j] = MFMA(xp[i], ql, a1[i][j]);
            }
        }
    }
#pragma unroll
    for (int i = 0; i < 2; ++i)
#pragma unroll
        for (int j = 0; j < 2; ++j) {
            int k1 = nq + 16 * j + fr;
            int mb = mq + 16 * i + qd * 4;
            ushort4 ph, pl;
            float v0 = a1[i][j][0], v1 = a1[i][j][1], v2 = a1[i][j][2], v3 = a1[i][j][3];
            ph.x = bfr(v0); ph.y = bfr(v1); ph.z = bfr(v2); ph.w = bfr(v3);
            pl.x = bfr(v0 - bff(ph.x)); pl.y = bfr(v1 - bff(ph.y));
            pl.z = bfr(v2 - bff(ph.z)); pl.w = bfr(v3 - bff(ph.w));
            *(ushort4*)&Uh[k1 * 72 + mb] = ph;
            *(ushort4*)&Ul[k1 * 72 + mb] = pl;
        }
    __syncthreads();
    f32x4 a2[2][2];
#pragma unroll
    for (int i = 0; i < 2; ++i)
#pragma unroll
        for (int j = 0; j < 2; ++j) a2[i][j] = (f32x4){0.f, 0.f, 0.f, 0.f};
#pragma unroll
    for (int ks = 0; ks < 2; ++ks) {
        const int k0 = ks * 32 + qd * 8;
        s16x8 uh[2], ul[2];
#pragma unroll
        for (int i = 0; i < 2; ++i) {
            uh[i] = *(const s16x8*)&Uh[(mq + 16 * i + fr) * 72 + k0];
            ul[i] = *(const s16x8*)&Ul[(mq + 16 * i + fr) * 72 + k0];
        }
#pragma unroll
        for (int j = 0; j < 2; ++j) {
            s16x8 qh = *(const s16x8*)&Ah[(nq + 16 * j + fr) * 72 + k0];
            s16x8 ql = *(const s16x8*)&Al[(nq + 16 * j + fr) * 72 + k0];
#pragma unroll
            for (int i = 0; i < 2; ++i) {
                a2[i][j] = MFMA(uh[i], qh, a2[i][j]);
                a2[i][j] = MFMA(uh[i], ql, a2[i][j]);
                a2[i][j] = MFMA(ul[i], qh, a2[i][j]);
            }
        }
    }
#pragma unroll
    for (int i = 0; i < 2; ++i)
#pragma unroll
        for (int j = 0; j < 2; ++j) {
            int k2 = nq + 16 * j + fr;
            int nb = mq + 16 * i + qd * 4;
            ushort4 pk;
            pk.x = bfr(a2[i][j][0]); pk.y = bfr(a2[i][j][1]);
            pk.z = bfr(a2[i][j][2]); pk.w = bfr(a2[i][j][3]);
            *(ushort4*)&dst[k2 * 64 + nb] = pk;
        }
}

// ---------------- transpose: t16 NCHW bf16 -> thi NHWC bf16 ----------------
__global__ __launch_bounds__(256) void k_tsplit(const u16* __restrict__ t16,
                                                u16* __restrict__ thi) {
    __shared__ float Ls[64][65];
    const int b = blockIdx.z, cg = blockIdx.y, pg = blockIdx.x;
    const int tid = threadIdx.x;
    const u16* src = t16 + ((long)b * 512 + cg * 64) * 4096 + pg * 64;
#pragma unroll
    for (int j = 0; j < 2; ++j) {
        int idx = tid + j * 256;
        int c = idx >> 3, p8 = (idx & 7) * 8;
        s16x8 v = *(const s16x8*)&src[(long)c * 4096 + p8];
#pragma unroll
        for (int q = 0; q < 8; ++q) Ls[c][p8 + q] = bff((u16)v[q]);
    }
    __syncthreads();
#pragma unroll
    for (int j = 0; j < 2; ++j) {
        int idx = tid + j * 256;
        int p = idx >> 3, c8 = idx & 7;
        s16x8 vh;
#pragma unroll
        for (int q = 0; q < 8; ++q) vh[q] = (short)bfr(Ls[c8 * 8 + q][p]);
        long addr = ((long)b * 4096 + pg * 64 + p) * 512 + cg * 64 + c8 * 8;
        *(s16x8*)&thi[addr] = vh;
    }
}

// ---------------- C-DCT GEMM + fused hist1 (Q direct from fragment-major global) ----------------
__global__ __launch_bounds__(256, 4) void k_cgemm(const u16* __restrict__ thi,
                                                  const u16* __restrict__ Akfh, const u16* __restrict__ Akfl,
                                                  float* __restrict__ D, unsigned* __restrict__ g1) {
    __shared__ __align__(16) short Ph[128 * 40];
    __shared__ unsigned hh[2048];
    const int b = blockIdx.z;
    const int p0 = blockIdx.y * 128, kc0 = blockIdx.x * 128;
    const int tid = threadIdx.x;
    const int lane = tid & 63, wave = tid >> 6;
    const int fr = lane & 15, qd = lane >> 4;
    const int mq = (wave >> 1) * 64, nq = (wave & 1) * 64;
    for (int t = tid; t < 2048; t += 256) hh[t] = 0u;
    f32x4 acc[4][4];
#pragma unroll
    for (int i = 0; i < 4; ++i)
#pragma unroll
        for (int j = 0; j < 4; ++j) acc[i][j] = (f32x4){0.f, 0.f, 0.f, 0.f};
    const u16* Pgh = thi + ((long)b * 4096 + p0) * 512;
    const int r0 = tid >> 2, q40 = (tid & 3) * 8;
    s16x8 psh[2];
#pragma unroll
    for (int j = 0; j < 2; ++j)
        psh[j] = *(const s16x8*)&Pgh[(long)(r0 + j * 64) * 512 + q40];
    const long qb0 = ((long)(kc0 >> 4) + (nq >> 4)) * 16 * 512 + (long)lane * 8;
    for (int ch = 0; ch < 16; ++ch) {
        __syncthreads();
#pragma unroll
        for (int j = 0; j < 2; ++j)
            *(s16x8*)&Ph[(r0 + j * 64) * 40 + q40] = psh[j];
        __syncthreads();
        if (ch < 15) {
            const int kn = (ch + 1) * 32;
#pragma unroll
            for (int j = 0; j < 2; ++j)
                psh[j] = *(const s16x8*)&Pgh[(long)(r0 + j * 64) * 512 + kn + q40];
        }
        const long qbase = qb0 + (long)ch * 512;
        s16x8 qfh[4], qfl[4];
#pragma unroll
        for (int j = 0; j < 4; ++j) {
            qfh[j] = *(const s16x8*)&Akfh[qbase + (long)j * 8192];
            qfl[j] = *(const s16x8*)&Akfl[qbase + (long)j * 8192];
        }
#pragma unroll
        for (int i = 0; i < 4; ++i) {
            s16x8 ph = *(const s16x8*)&Ph[(mq + 16 * i + fr) * 40 + qd * 8];
#pragma unroll
            for (int j = 0; j < 4; ++j) {
                acc[i][j] = MFMA(ph, qfh[j], acc[i][j]);
                acc[i][j] = MFMA(ph, qfl[j], acc[i][j]);
            }
        }
    }
#pragma unroll
    for (int i = 0; i < 4; ++i)
#pragma unroll
        for (int j = 0; j < 4; ++j) {
            int rowb = mq + 16 * i + qd * 4;
            int col = kc0 + nq + 16 * j + fr;
#pragma unroll
            for (int r = 0; r < 4; ++r) {
                float v = acc[i][j][r];
                D[((long)b * 4096 + p0 + rowb + r) * 512 + col] = v;
                unsigned bin = __float_as_uint(fabsf(v)) >> 19;
                atomicAdd(&hh[bin & 2047u], 1u << ((bin >> 11) << 4));
            }
        }
    __syncthreads();
    for (int t = tid; t < 2048; t += 256) {
        unsigned c = hh[t];
        unsigned lo = c & 0xffffu, hi = c >> 16;
        if (lo) atomicAdd(&g1[t], lo);
        if (hi) atomicAdd(&g1[t + 2048], hi);
    }
}

// ---------------- selection ----------------
__global__ void k_scan1(const unsigned* __restrict__ hist, unsigned* __restrict__ sel) {
    __shared__ unsigned chunk[256];
    __shared__ unsigned above[256];
    const int t = threadIdx.x;
    unsigned s = 0;
#pragma unroll
    for (int j = 0; j < 16; ++j) s += hist[t * 16 + j];
    chunk[t] = s;
    __syncthreads();
    if (t == 0) {
        unsigned a = 0;
        for (int c = 255; c >= 0; --c) { above[c] = a; a += chunk[c]; }
    }
    __syncthreads();
    const unsigned kv[4] = {4194304u, 1048576u, 262144u, 65536u};
    unsigned run = above[t];
    for (int j = 15; j >= 0; --j) {
        unsigned bin = t * 16 + j;
        unsigned hb = hist[bin];
        unsigned Sab = run;
        run += hb;
#pragma unroll
        for (int i = 0; i < 4; ++i)
            if (run >= kv[i] && Sab < kv[i]) { sel[i] = bin; sel[4 + i] = kv[i] - Sab; }
    }
}

__global__ __launch_bounds__(256) void k_compact(const float4* __restrict__ D,
                                                 const unsigned* __restrict__ sel,
                                                 unsigned* __restrict__ cand,
                                                 unsigned* __restrict__ cnt) {
    __shared__ unsigned lctr;
    if (threadIdx.x == 0) lctr = 0u;
    __syncthreads();
    const unsigned p0 = sel[0], p1 = sel[1], p2 = sel[2], p3 = sel[3];
    const int lane = threadIdx.x & 63;
    unsigned* slice = cand + (long)blockIdx.x * 4096;
    const long n4 = TOT / 4;
    for (long idx = (long)blockIdx.x * 256 + threadIdx.x; idx < n4; idx += (long)gridDim.x * 256) {
        float4 v = D[idx];
        float f[4] = {v.x, v.y, v.z, v.w};
#pragma unroll
        for (int q = 0; q < 4; ++q) {
            unsigned u = __float_as_uint(fabsf(f[q]));
            unsigned pre = u >> 19;
            bool m = (pre == p0) | (pre == p1) | (pre == p2) | (pre == p3);
            unsigned long long mask = __ballot(m);
            if (mask) {
                int leader = __ffsll((long long)mask) - 1;
                unsigned base = 0;
                if (lane == leader) base = atomicAdd(&lctr, (unsigned)__popcll(mask));
                base = (unsigned)__shfl((int)base, leader);
                if (m) {
                    unsigned pos = base + (unsigned)__popcll(mask & ((1ULL << lane) - 1ULL));
                    if (pos < 4096u) slice[pos] = u;
                }
            }
        }
    }
    __syncthreads();
    if (threadIdx.x == 0) cnt[blockIdx.x] = lctr < 4096u ? lctr : 4096u;
}

__global__ __launch_bounds__(256) void k_hist2c(const unsigned* __restrict__ cand,
                                                const unsigned* __restrict__ cnt,
                                                const unsigned* __restrict__ sel,
                                                unsigned* __restrict__ partial) {
    __shared__ unsigned h[4096];
    for (int i = threadIdx.x; i < 4096; i += 256) h[i] = 0u;
    __syncthreads();
    const unsigned p0 = sel[0], p1 = sel[1], p2 = sel[2], p3 = sel[3];
    for (int s = 0; s < 8; ++s) {
        int slice = blockIdx.x * 8 + s;
        unsigned n = cnt[slice];
        const unsigned* L = cand + (long)slice * 4096;
        for (unsigned i = threadIdx.x; i < n; i += 256) {
            unsigned u = L[i];
            unsigned pre = u >> 19, mid = (u >> 9) & 1023u;
            if (pre == p0) atomicAdd(&h[mid], 1u);
            else if (pre == p1) atomicAdd(&h[1024 + mid], 1u);
            else if (pre == p2) atomicAdd(&h[2048 + mid], 1u);
            else if (pre == p3) atomicAdd(&h[3072 + mid], 1u);
        }
    }
    __syncthreads();
    unsigned* dst = partial + (long)blockIdx.x * 4096;
    for (int i = threadIdx.x; i < 4096; i += 256) dst[i] = h[i];
}

__global__ __launch_bounds__(256) void k_red(const unsigned* __restrict__ partial,
                                             unsigned* __restrict__ out, int nbins, int nrows) {
    int bin = blockIdx.x * 256 + threadIdx.x;
    if (bin >= nbins) return;
    unsigned s = 0;
#pragma unroll 16
    for (int r = 0; r < nrows; ++r) s += partial[(long)r * nbins + bin];
    out[bin] = s;
}

__global__ void k_scan2(const unsigned* __restrict__ hist2, unsigned* __restrict__ sel) {
    __shared__ unsigned chunk[256];
    __shared__ unsigned above[256];
    const int t = threadIdx.x;
    for (int i = 0; i < 4; ++i) {
        const unsigned* h = hist2 + i * 1024;
        unsigned r = sel[4 + i];
        unsigned s = h[t * 4] + h[t * 4 + 1] + h[t * 4 + 2] + h[t * 4 + 3];
        chunk[t] = s;
        __syncthreads();
        if (t == 0) {
            unsigned a = 0;
            for (int c = 255; c >= 0; --c) { above[c] = a; a += chunk[c]; }
        }
        __syncthreads();
        unsigned run = above[t];
        for (int j = 3; j >= 0; --j) {
            unsigned bin = t * 4 + j;
            unsigned hb = h[bin];
            unsigned Sab = run;
            run += hb;
            if (run >= r && Sab < r) { sel[8 + i] = bin; sel[12 + i] = r - Sab; }
        }
        __syncthreads();
    }
}

__global__ __launch_bounds__(256) void k_hist3c(const unsigned* __restrict__ cand,
                                                const unsigned* __restrict__ cnt,
                                                const unsigned* __restrict__ sel,
                                                unsigned* __restrict__ partial) {
    __shared__ unsigned h[2048];
    for (int i = threadIdx.x; i < 2048; i += 256) h[i] = 0u;
    __syncthreads();
    unsigned pre2[4];
#pragma unroll
    for (int i = 0; i < 4; ++i) pre2[i] = (sel[i] << 10) | sel[8 + i];
    for (int s = 0; s < 8; ++s) {
        int slice = blockIdx.x * 8 + s;
        unsigned n = cnt[slice];
        const unsigned* L = cand + (long)slice * 4096;
        for (unsigned i = threadIdx.x; i < n; i += 256) {
            unsigned u = L[i];
            unsigned p = u >> 9, low = u & 511u;
            if (p == pre2[0]) atomicAdd(&h[low], 1u);
            else if (p == pre2[1]) atomicAdd(&h[512 + low], 1u);
            else if (p == pre2[2]) atomicAdd(&h[1024 + low], 1u);
            else if (p == pre2[3]) atomicAdd(&h[1536 + low], 1u);
        }
    }
    __syncthreads();
    unsigned* dst = partial + (long)blockIdx.x * 2048;
    for (int i = threadIdx.x; i < 2048; i += 256) dst[i] = h[i];
}

__global__ void k_scan3(const unsigned* __restrict__ hist3, const unsigned* __restrict__ sel,
                        float* __restrict__ thr) {
    __shared__ unsigned chunk[256];
    __shared__ unsigned above[256];
    const int t = threadIdx.x;
    for (int i = 0; i < 4; ++i) {
        const unsigned* h = hist3 + i * 512;
        unsigned r = sel[12 + i];
        unsigned s = h[t * 2] + h[t * 2 + 1];
        chunk[t] = s;
        __syncthreads();
        if (t == 0) {
            unsigned a = 0;
            for (int c = 255; c >= 0; --c) { above[c] = a; a += chunk[c]; }
        }
        __syncthreads();
        unsigned run = above[t];
        for (int j = 1; j >= 0; --j) {
            unsigned bin = t * 2 + j;
            unsigned hb = h[bin];
            unsigned Sab = run;
            run += hb;
            if (run >= r && Sab < r)
                thr[i] = __uint_as_float((sel[i] << 19) | (sel[8 + i] << 9) | bin);
        }
        __syncthreads();
    }
}

// ---------------- conv1 fused with IDCT_C (G direct from fragment-major global) ----------------
__global__ __launch_bounds__(256, 4) void k_conv1(const float* __restrict__ D, const u16* __restrict__ Gf,
                                                  const float* __restrict__ thrp, u16* __restrict__ h1pre) {
    __shared__ __align__(16) short Pt[128 * 40];
    const int b = blockIdx.z, br = blockIdx.y, p0 = blockIdx.x * 128;
    const int z2 = br * 8 + b;
    const float thr = thrp[br];
    const int tid = threadIdx.x;
    const int lane = tid & 63, wave = tid >> 6;
    const int fr = lane & 15, qd = lane >> 4;
    const int mq = (wave >> 1) * 64, nq = (wave & 1) * 64;
    f32x4 acc[4][4];
#pragma unroll
    for (int i = 0; i < 4; ++i)
#pragma unroll
        for (int j = 0; j < 4; ++j) acc[i][j] = (f32x4){0.f, 0.f, 0.f, 0.f};
    const float* Pg = D + ((long)b * 4096 + p0) * 512;
    const int r0 = tid >> 2, q40 = (tid & 3) * 8;
    float4 da[2], db[2];
#pragma unroll
    for (int j = 0; j < 2; ++j) {
        const float* src = &Pg[(long)(r0 + j * 64) * 512 + q40];
        da[j] = *(const float4*)src;
        db[j] = *(const float4*)(src + 4);
    }
    const long qb0 = (((long)br * 16) * 8 + (nq >> 4)) * 512 + (long)lane * 8;
    for (int ch = 0; ch < 16; ++ch) {
        const int k0 = ch * 32;
        __syncthreads();
#pragma unroll
        for (int j = 0; j < 2; ++j) {
            int r = r0 + j * 64;
            s16x8 m;
            float f[8] = {da[j].x, da[j].y, da[j].z, da[j].w, db[j].x, db[j].y, db[j].z, db[j].w};
#pragma unroll
            for (int q = 0; q < 8; ++q) m[q] = (short)(fabsf(f[q]) >= thr ? bfr(f[q]) : (u16)0);
            *(s16x8*)&Pt[r * 40 + q40] = m;
        }
        __syncthreads();
        if (ch < 15) {
            const int kn = k0 + 32;
#pragma unroll
            for (int j = 0; j < 2; ++j) {
                const float* src = &Pg[(long)(r0 + j * 64) * 512 + kn + q40];
                da[j] = *(const float4*)src;
                db[j] = *(const float4*)(src + 4);
            }
        }
        const long qbase = qb0 + (long)ch * 4096;
        s16x8 qb[4];
#pragma unroll
        for (int j = 0; j < 4; ++j) qb[j] = *(const s16x8*)&Gf[qbase + (long)j * 512];
#pragma unroll
        for (int i = 0; i < 4; ++i) {
            s16x8 pa = *(const s16x8*)&Pt[(mq + 16 * i + fr) * 40 + qd * 8];
#pragma unroll
            for (int j = 0; j < 4; ++j) acc[i][j] = MFMA(pa, qb[j], acc[i][j]);
        }
    }
#pragma unroll
    for (int i = 0; i < 4; ++i)
#pragma unroll
        for (int j = 0; j < 4; ++j) {
            int rowb = p0 + mq + 16 * i + qd * 4;
            int o = nq + 16 * j + fr;
            ushort4 pk;
            pk.x = bfr(acc[i][j][0]); pk.y = bfr(acc[i][j][1]);
            pk.z = bfr(acc[i][j][2]); pk.w = bfr(acc[i][j][3]);
            *(ushort4*)&h1pre[((long)z2 * 128 + o) * 4096 + rowb] = pk;
        }
}

// ---------------- IDCT passes ----------------
__global__ __launch_bounds__(256, 4) void k_idct1(const u16* __restrict__ h1pre, const u16* __restrict__ AcT,
                                                  u16* __restrict__ X2) {
    __shared__ __align__(16) short Pt[128 * 72];
    __shared__ __align__(16) short Qt[64 * 72];
    const int b = blockIdx.z, br = blockIdx.y, m0 = blockIdx.x * 128;
    const int z2 = br * 8 + b;
    const int tid = threadIdx.x;
    const int lane = tid & 63, wave = tid >> 6;
    const int fr = lane & 15, qd = lane >> 4;
    const int mq = wave * 32;
    const u16* Pg = h1pre + (long)z2 * 524288 + (long)m0 * 64;
    f32x4 acc[2][4];
#pragma unroll
    for (int i = 0; i < 2; ++i)
#pragma unroll
        for (int j = 0; j < 4; ++j) acc[i][j] = (f32x4){0.f, 0.f, 0.f, 0.f};
#pragma unroll
    for (int j = 0; j < 4; ++j) {
        int idx = tid + j * 256;
        int r = idx >> 3, q8 = (idx & 7) * 8;
        *(s16x8*)&Pt[r * 72 + q8] = *(const s16x8*)&Pg[(long)r * 64 + q8];
    }
#pragma unroll
    for (int j = 0; j < 2; ++j) {
        int idx = tid + j * 256;
        int r = idx >> 3, q8 = (idx & 7) * 8;
        *(s16x8*)&Qt[r * 72 + q8] = *(const s16x8*)&AcT[(long)r * 64 + q8];
    }
    __syncthreads();
#pragma unroll
    for (int ks = 0; ks < 2; ++ks) {
        s16x8 pa[2], qb[4];
#pragma unroll
        for (int i = 0; i < 2; ++i) pa[i] = *(const s16x8*)&Pt[(mq + 16 * i + fr) * 72 + ks * 32 + qd * 8];
#pragma unroll
        for (int j = 0; j < 4; ++j) qb[j] = *(const s16x8*)&Qt[(16 * j + fr) * 72 + ks * 32 + qd * 8];
#pragma unroll
        for (int i = 0; i < 2; ++i)
#pragma unroll
            for (int j = 0; j < 4; ++j) acc[i][j] = MFMA(pa[i], qb[j], acc[i][j]);
    }
#pragma unroll
    for (int i = 0; i < 2; ++i)
#pragma unroll
        for (int j = 0; j < 4; ++j) {
            int Rb = m0 + mq + 16 * i + qd * 4;
            int o = Rb >> 6, y = Rb & 63;
            int xo = 16 * j + fr;
            ushort4 pk;
            pk.x = bfr(acc[i][j][0]); pk.y = bfr(acc[i][j][1]);
            pk.z = bfr(acc[i][j][2]); pk.w = bfr(acc[i][j][3]);
            *(ushort4*)&X2[(long)z2 * 524288 + ((long)xo * 128 + o) * 64 + y] = pk;
        }
}

__global__ __launch_bounds__(256, 4) void k_idct2(const u16* __restrict__ X2, const u16* __restrict__ AcT,
                                                  const float* __restrict__ b1, u16* __restrict__ h1) {
    __shared__ __align__(16) short Pt[128 * 72];
    __shared__ __align__(16) short Qt[64 * 72];
    const int b = blockIdx.z, br = blockIdx.y, m0 = blockIdx.x * 128;
    const int z2 = br * 8 + b;
    const int tid = threadIdx.x;
    const int lane = tid & 63, wave = tid >> 6;
    const int fr = lane & 15, qd = lane >> 4;
    const int mq = wave * 32;
    const u16* Pg = X2 + (long)z2 * 524288 + (long)m0 * 64;
    f32x4 acc[2][4];
#pragma unroll
    for (int i = 0; i < 2; ++i)
#pragma unroll
        for (int j = 0; j < 4; ++j) acc[i][j] = (f32x4){0.f, 0.f, 0.f, 0.f};
#pragma unroll
    for (int j = 0; j < 4; ++j) {
        int idx = tid + j * 256;
        int r = idx >> 3, q8 = (idx & 7) * 8;
        *(s16x8*)&Pt[r * 72 + q8] = *(const s16x8*)&Pg[(long)r * 64 + q8];
    }
#pragma unroll
    for (int j = 0; j < 2; ++j) {
        int idx = tid + j * 256;
        int r = idx >> 3, q8 = (idx & 7) * 8;
        *(s16x8*)&Qt[r * 72 + q8] = *(const s16x8*)&AcT[(long)r * 64 + q8];
    }
    __syncthreads();
#pragma unroll
    for (int ks = 0; ks < 2; ++ks) {
        s16x8 pa[2], qb[4];
#pragma unroll
        for (int i = 0; i < 2; ++i) pa[i] = *(const s16x8*)&Pt[(mq + 16 * i + fr) * 72 + ks * 32 + qd * 8];
#pragma unroll
        for (int j = 0; j < 4; ++j) qb[j] = *(const s16x8*)&Qt[(16 * j + fr) * 72 + ks * 32 + qd * 8];
#pragma unroll
        for (int i = 0; i < 2; ++i)
#pragma unroll
            for (int j = 0; j < 4; ++j) acc[i][j] = MFMA(pa[i], qb[j], acc[i][j]);
    }
#pragma unroll
    for (int i = 0; i < 2; ++i)
#pragma unroll
        for (int j = 0; j < 4; ++j) {
            int Rb = m0 + mq + 16 * i + qd * 4;
            int xo = Rb >> 7, o = Rb & 127;
            int yo = 16 * j + fr;
            ushort4 pk;
            const float* bg = b1 + br * 128 + o;
            pk.x = bfr(fmaxf(acc[i][j][0] + bg[0], 0.f));
            pk.y = bfr(fmaxf(acc[i][j][1] + bg[1], 0.f));
            pk.z = bfr(fmaxf(acc[i][j][2] + bg[2], 0.f));
            pk.w = bfr(fmaxf(acc[i][j][3] + bg[3], 0.f));
            *(ushort4*)&h1[(long)z2 * 524288 + ((long)yo * 64 + xo) * 128 + o] = pk;
        }
}

// ---------------- conv2: implicit GEMM (W direct from fragment-major global) ----------------
__global__ __launch_bounds__(256, 4) void k_conv2(const u16* __restrict__ h1, const u16* __restrict__ W2f,
                                                  const float* __restrict__ b2, u16* __restrict__ h2) {
    __shared__ __align__(16) short Pt[128 * 40];
    const int b = blockIdx.z, br = blockIdx.y;
    const int bx = blockIdx.x;
    const int y0 = ((bx & 7) * 4 + (bx >> 3)) * 2;   // XCD-aware y-tile swizzle
    const int z2 = br * 8 + b;
    const int tid = threadIdx.x;
    const int lane = tid & 63, wave = tid >> 6;
    const int fr = lane & 15, qd = lane >> 4;
    const int mq = (wave >> 1) * 64, nq = (wave & 1) * 64;
    f32x4 acc[4][4];
#pragma unroll
    for (int i = 0; i < 4; ++i)
#pragma unroll
        for (int j = 0; j < 4; ++j) acc[i][j] = (f32x4){0.f, 0.f, 0.f, 0.f};
    const u16* hb = h1 + (long)z2 * 524288;
    const int r0 = tid >> 2, q40 = (tid & 3) * 8;
    s16x8 preg[2];
    auto loadP = [&](int ch) {
        const int t9 = ch >> 2, ci0 = (ch & 3) * 32;
        const int ky = t9 / 3, kx = t9 - 3 * ky;
        const int dy = 2 * ky - 2, dx = 2 * kx - 2;
#pragma unroll
        for (int j = 0; j < 2; ++j) {
            int r = r0 + j * 64;
            int ry = r >> 6, xx = r & 63;
            int ysrc = y0 + ry + dy, xsrc = xx + dx;
            s16x8 v = {0, 0, 0, 0, 0, 0, 0, 0};
            if ((unsigned)ysrc < 64u && (unsigned)xsrc < 64u)
                v = *(const s16x8*)&hb[((long)ysrc * 64 + xsrc) * 128 + ci0 + q40];
            preg[j] = v;
        }
    };
    loadP(0);
    const long qb0 = (((long)br * 36) * 8 + (nq >> 4)) * 512 + (long)lane * 8;
    for (int ch = 0; ch < 36; ++ch) {
        __syncthreads();
#pragma unroll
        for (int j = 0; j < 2; ++j)
            *(s16x8*)&Pt[(r0 + j * 64) * 40 + q40] = preg[j];
        __syncthreads();
        if (ch < 35) loadP(ch + 1);
        const long qbase = qb0 + (long)ch * 4096;
        s16x8 qb[4];
#pragma unroll
        for (int j = 0; j < 4; ++j) qb[j] = *(const s16x8*)&W2f[qbase + (long)j * 512];
#pragma unroll
        for (int i = 0; i < 4; ++i) {
            s16x8 pa = *(const s16x8*)&Pt[(mq + 16 * i + fr) * 40 + qd * 8];
#pragma unroll
            for (int j = 0; j < 4; ++j) acc[i][j] = MFMA(pa, qb[j], acc[i][j]);
        }
    }
#pragma unroll
    for (int i = 0; i < 4; ++i)
#pragma unroll
        for (int j = 0; j < 4; ++j) {
            int rowb = mq + 16 * i + qd * 4;
            int o = nq + 16 * j + fr;
            float bb = b2[br * 128 + o];
#pragma unroll
            for (int r = 0; r < 4; ++r) {
                float v = fmaxf(acc[i][j][r] + bb, 0.f);
                h2[(long)z2 * 524288 + ((long)y0 * 64 + rowb + r) * 128 + o] = bfr(v);
            }
        }
}

// ---------------- conv3: writes bf16 logits in [b][m][c][n] layout ----------------
__global__ __launch_bounds__(256, 4) void k_conv3(const u16* __restrict__ h2, const u16* __restrict__ W3f,
                                                  const float* __restrict__ b3, u16* __restrict__ lgn) {
    __shared__ __align__(16) short buf[18432];
    short* Pt = buf;
    const int b = blockIdx.z, br = blockIdx.y, p0 = blockIdx.x * 128;
    const int z2 = br * 8 + b;
    const int m0 = blockIdx.x * 2;
    const int tid = threadIdx.x;
    const int lane = tid & 63, wave = tid >> 6;
    const int fr = lane & 15, qd = lane >> 4;
    const int mq = (wave >> 1) * 64, nq = (wave & 1) * 64;
    f32x4 acc[4][4];
#pragma unroll
    for (int i = 0; i < 4; ++i)
#pragma unroll
        for (int j = 0; j < 4; ++j) acc[i][j] = (f32x4){0.f, 0.f, 0.f, 0.f};
    const u16* Pg = h2 + (long)z2 * 524288 + (long)p0 * 128;
    const long qb0 = (((long)br * 4) * 8 + (nq >> 4)) * 512 + (long)lane * 8;
    for (int ch = 0; ch < 4; ++ch) {
        const int k0 = ch * 32;
        __syncthreads();
#pragma unroll
        for (int j = 0; j < 2; ++j) {
            int idx = tid + j * 256;
            int r = idx >> 2, q4 = (idx & 3) * 8;
            *(s16x8*)&Pt[r * 40 + q4] = *(const s16x8*)&Pg[(long)r * 128 + k0 + q4];
        }
        __syncthreads();
        const long qbase = qb0 + (long)ch * 4096;
        s16x8 qb[4];
#pragma unroll
        for (int j = 0; j < 4; ++j) qb[j] = *(const s16x8*)&W3f[qbase + (long)j * 512];
#pragma unroll
        for (int i = 0; i < 4; ++i) {
            s16x8 pa = *(const s16x8*)&Pt[(mq + 16 * i + fr) * 40 + qd * 8];
#pragma unroll
            for (int j = 0; j < 4; ++j) acc[i][j] = MFMA(pa, qb[j], acc[i][j]);
        }
    }
    __syncthreads();
#pragma unroll
    for (int i = 0; i < 4; ++i)
#pragma unroll
        for (int j = 0; j < 4; ++j) {
            int l = mq + 16 * i + qd * 4;
            int mrow = l >> 6, nn = l & 63;
            int o = nq + 16 * j + fr;
            float bb = b3[br * 128 + o];
            ushort4 pk;
            pk.x = bfr(fmaxf(acc[i][j][0] + bb, 0.f));
            pk.y = bfr(fmaxf(acc[i][j][1] + bb, 0.f));
            pk.z = bfr(fmaxf(acc[i][j][2] + bb, 0.f));
            pk.w = bfr(fmaxf(acc[i][j][3] + bb, 0.f));
            *(ushort4*)&buf[mrow * 9216 + o * 72 + nn] = pk;
        }
    __syncthreads();
#pragma unroll
    for (int t = 0; t < 16; ++t) {
        int u = tid + t * 256;
        int mrow = u >> 11;
        int rem = u & 2047;
        int cl = rem >> 4, n4 = (rem & 15) << 2;
        ushort4 v = *(const ushort4*)&buf[mrow * 9216 + cl * 72 + n4];
        long dst = (((long)b * 64 + m0 + mrow) * 512 + br * 128 + cl) * 64 + n4;
        *(ushort4*)&lgn[dst] = v;
    }
}

// ---------------- softmax gating + residual (lgn [b][m][c][n], vectorized) ----------------
__global__ __launch_bounds__(256) void k_final(const float* __restrict__ x, const u16* __restrict__ lgn,
                                               float* __restrict__ out) {
    const int b = blockIdx.y, m = blockIdx.x;
    const int tid = threadIdx.x;
    const int csub = tid >> 3, oct = tid & 7;
    const u16* L = lgn + ((long)b * 64 + m) * 512 * 64;
    __shared__ float redm[32][64];
    __shared__ float reds[32][64];
    __shared__ float Mf[64], Sf[64];
    float mx[8], sm[8];
#pragma unroll
    for (int q = 0; q < 8; ++q) { mx[q] = -1e30f; sm[q] = 0.f; }
#pragma unroll 4
    for (int k = 0; k < 16; ++k) {
        int c = csub * 16 + k;
        s16x8 v8 = *(const s16x8*)&L[c * 64 + oct * 8];
#pragma unroll
        for (int q = 0; q < 8; ++q) {
            float v = bff((u16)v8[q]);
            float mn = fmaxf(mx[q], v);
            sm[q] = sm[q] * __expf(mx[q] - mn) + __expf(v - mn);
            mx[q] = mn;
        }
    }
#pragma unroll
    for (int q = 0; q < 8; ++q) {
        redm[csub][oct * 8 + q] = mx[q];
        reds[csub][oct * 8 + q] = sm[q];
    }
    __syncthreads();
    if (tid < 64) {
        float M = -1e30f;
#pragma unroll 8
        for (int g = 0; g < 32; ++g) M = fmaxf(M, redm[g][tid]);
        float S = 0.f;
#pragma unroll 8
        for (int g = 0; g < 32; ++g) S += reds[g][tid] * __expf(redm[g][tid] - M);
        Mf[tid] = M;
        Sf[tid] = 1.0f / S;
    }
    __syncthreads();
    float Mv[8], Iv[8];
#pragma unroll
    for (int q = 0; q < 8; ++q) { Mv[q] = Mf[oct * 8 + q]; Iv[q] = Sf[oct * 8 + q]; }
    const long xb = (long)b * 512 * 4096 + m * 64 + oct * 8;
#pragma unroll 4
    for (int k = 0; k < 16; ++k) {
        int c = csub * 16 + k;
        s16x8 v8 = *(const s16x8*)&L[c * 64 + oct * 8];
        long a = xb + (long)c * 4096;
        float4 x0 = *(const float4*)&x[a];
        float4 x1 = *(const float4*)&x[a + 4];
        float xf[8] = {x0.x, x0.y, x0.z, x0.w, x1.x, x1.y, x1.z, x1.w};
        float r[8];
#pragma unroll
        for (int q = 0; q < 8; ++q) {
            float w = __expf(bff((u16)v8[q]) - Mv[q]) * Iv[q];
            r[q] = xf[q] * w + xf[q];
        }
        *(float4*)&out[a] = make_float4(r[0], r[1], r[2], r[3]);
        *(float4*)&out[a + 4] = make_float4(r[4], r[5], r[6], r[7]);
    }
}

// ---------------------------------------------------------------------------
extern "C" void kernel_launch(void* const* d_in, const int* in_sizes, int n_in,
                              void* d_out, int out_size, void* d_ws, size_t ws_size,
                              hipStream_t stream) {
    (void)in_sizes; (void)n_in; (void)out_size; (void)ws_size;
    const float* x  = (const float*)d_in[0];
    const float* W1 = (const float*)d_in[1];
    const float* b1 = (const float*)d_in[2];
    const float* W2 = (const float*)d_in[3];
    const float* b2 = (const float*)d_in[4];
    const float* W3 = (const float*)d_in[5];
    const float* b3 = (const float*)d_in[6];
    float* out = (float*)d_out;
    float* ws = (float*)d_ws;

    u16*   t16  = (u16*)(ws + OFF_T);
    unsigned* cand = (unsigned*)(ws + OFF_CAND);
    unsigned* cnt  = (unsigned*)(ws + OFF_CNT);
    unsigned* p2   = (unsigned*)(ws + OFF_P2);
    unsigned* p3   = (unsigned*)(ws + OFF_P3);
    unsigned* h2r  = (unsigned*)(ws + OFF_H2R);
    unsigned* h3r  = (unsigned*)(ws + OFF_H3R);
    u16*   h1pre= (u16*)(ws + OFF_H1P);
    u16*   lgn  = (u16*)(ws + OFF_H1P);
    u16*   X2   = (u16*)(ws + OFF_X2);
    u16*   thi  = (u16*)(ws + OFF_THI);
    u16*   h1   = (u16*)(ws + OFF_H1);
    u16*   Akfh = (u16*)(ws + OFF_AKFH);
    u16*   Akfl = (u16*)(ws + OFF_AKFL);
    u16*   Gf   = (u16*)(ws + OFF_GF);
    float* D    = ws + OFF_D;
    float* ctab = ws + OFF_D;
    u16*   h2   = (u16*)(ws + OFF_H2);
    u16*   Akh  = (u16*)(ws + OFF_AKH);
    u16*   Akl  = (u16*)(ws + OFF_AKL);
    u16*   AcT  = (u16*)(ws + OFF_ACT);
    u16*   Gb   = (u16*)(ws + OFF_GBF);
    u16*   W2f  = (u16*)(ws + OFF_W2A);
    u16*   W3f  = (u16*)(ws + OFF_W3B);
    unsigned* hist1 = (unsigned*)(ws + OFF_HIST);
    unsigned* sel   = (unsigned*)(ws + OFF_SEL);
    float* thr      = ws + OFF_THR;
    u16*   Ach  = (u16*)(ws + OFF_ACH);
    u16*   Acl  = (u16*)(ws + OFF_ACL);

    k_ctab<<<8, 256, 0, stream>>>(ctab);
    k_build_mats<<<1024, 256, 0, stream>>>(ctab, Akh, Akl, Akfh, Akfl, AcT, Ach, Acl);
    k_zero<<<16, 256, 0, stream>>>(hist1, 4096);
    k_gmm<<<dim3(4, 4), 256, 0, stream>>>(W1, Akh, Akl, Gb);
    k_gf<<<128, 256, 0, stream>>>(Gb, Gf);
    k_wprep<<<2304, 256, 0, stream>>>(W2, W3, W2f, W3f);

    // forward spatial DCT via MFMA -> t16 NCHW bf16
    k_tile_fwd<<<4096, 256, 0, stream>>>(x, t16, Ach, Acl);
    // transpose to NHWC bf16
    k_tsplit<<<dim3(64, 8, 8), 256, 0, stream>>>(t16, thi);
    // C-axis DCT via bf16 MFMA -> D fp32 NHWC (+ fused hist1)
    k_cgemm<<<dim3(4, 32, 8), 256, 0, stream>>>(thi, Akfh, Akfl, D, hist1);

    // exact top-k thresholds
    k_scan1<<<1, 256, 0, stream>>>(hist1, sel);
    k_compact<<<2048, 256, 0, stream>>>((const float4*)D, sel, cand, cnt);
    k_hist2c<<<256, 256, 0, stream>>>(cand, cnt, sel, p2);
    k_red<<<16, 256, 0, stream>>>(p2, h2r, 4096, 256);
    k_scan2<<<1, 256, 0, stream>>>(h2r, sel);
    k_hist3c<<<256, 256, 0, stream>>>(cand, cnt, sel, p3);
    k_red<<<8, 256, 0, stream>>>(p3, h3r, 2048, 256);
    k_scan3<<<1, 256, 0, stream>>>(h3r, sel, thr);

    // branches (all 4 concurrent via grid.y)
    k_conv1<<<dim3(32, 4, 8), 256, 0, stream>>>(D, Gf, thr, h1pre);
    k_idct1<<<dim3(64, 4, 8), 256, 0, stream>>>(h1pre, AcT, X2);
    k_idct2<<<dim3(64, 4, 8), 256, 0, stream>>>(X2, AcT, b1, h1);
    k_conv2<<<dim3(32, 4, 8), 256, 0, stream>>>(h1, W2f, b2, h2);
    k_conv3<<<dim3(32, 4, 8), 256, 0, stream>>>(h2, W3f, b3, lgn);

    k_final<<<dim3(64, 8), 256, 0, stream>>>(x, lgn, out);
}

// Round 9
// 419.412 us; speedup vs baseline: 1.1577x; 1.1577x over previous
//
#include <hip/hip_runtime.h>
#include <math.h>

#define NB   8
#define NC   512
#define SP   4096
#define TOT  16777216L
static const double PI_D = 3.14159265358979323846;

typedef short s16x8 __attribute__((ext_vector_type(8)));
typedef float f32x4 __attribute__((ext_vector_type(4)));
typedef unsigned short u16;

// ---------------- ws layout (float units) ----------------
// region A [0,16777216): t16 [0,8.39M); cand [0,8.39M); partials+Gf [8.39M,10.1M);
//   h1pre/lgn [0,8.39M); X2 [8.39M,16.78M)
// region B [16777216,25165824): thi (FULL region); later h1
// region C [25165824,41943040): ctab (setup); D16 u16 [25165824,33554432); later h2 (same spot,
//   written after conv1 consumes D16)
#define OFF_T    0L
#define OFF_CAND 0L                   // u32[2048*4096] candidate slices (32 MB)
#define OFF_CNT  8388608L             // u32[2048] per-block counts
#define OFF_GF   9971712L             // u16[262144] Gf fragment-major (conv1; dies at idct1)
#define OFF_H1P  0L                   // h1pre bf16 [32][128][4096]; later lgn (same size)
#define OFF_X2   8388608L
#define OFF_THI  16777216L            // thi u16[16.78M] spans ALL of region B
#define OFF_H1   16777216L            // h1 occupies region B AFTER idct2
#define OFF_D    25165824L            // D16 u16[16.78M]; ctab float[2048] during setup only
#define OFF_H2   25165824L
#define OFF_AKH  42205184L
#define OFF_AKL  42336256L
#define OFF_ACT  42467328L
#define OFF_GBF  42468352L
#define OFF_W2A  42599424L            // W2f fragment-major
#define OFF_W3B  42894336L            // W3f fragment-major
#define OFF_HIST 42927104L            // hist1 4096 (u32) + h2r2 32 (u32) right after
#define OFF_SEL  42937344L            // u32[16]
#define OFF_ACH  42937368L            // u16[4096] A64 hi
#define OFF_ACL  42939416L            // u16[4096] A64 lo

__device__ inline u16 bfr(float x) {
    unsigned u = __float_as_uint(x);
    unsigned r = u + 0x7fffu + ((u >> 16) & 1u);
    return (u16)(r >> 16);
}
__device__ inline float bff(u16 h) { return __uint_as_float(((unsigned)h) << 16); }

#define MFMA(a, b, c) __builtin_amdgcn_mfma_f32_16x16x32_bf16((a), (b), (c), 0, 0, 0)

// ---------------- setup kernels ----------------
__global__ void k_ctab(float* __restrict__ ctab) {
    int m = blockIdx.x * 256 + threadIdx.x;
    if (m < 2048) ctab[m] = (float)cos(PI_D * (double)m / 1024.0);
}

__global__ void k_build_mats(const float* __restrict__ ctab,
                             u16* __restrict__ Akh, u16* __restrict__ Akl,
                             u16* __restrict__ AcT, u16* __restrict__ Ach, u16* __restrict__ Acl) {
    int idx = blockIdx.x * 256 + threadIdx.x;
    if (idx < 512 * 512) {
        int i = idx >> 9, j = idx & 511;
        float c = ctab[(i * (2 * j + 1)) & 2047];
        float f = c * (i == 0 ? 0.04419417382415922f : 0.0625f);
        u16 h = bfr(f);
        Akh[idx] = h;
        Akl[idx] = bfr(f - bff(h));
    }
    if (idx < 64 * 64) {
        int i = idx >> 6, j = idx & 63;
        float c = ctab[(8 * i * (2 * j + 1)) & 2047];
        float a = c * (i == 0 ? 0.125f : 0.17677669529663687f);
        u16 ah = bfr(a);
        Ach[idx] = ah;
        Acl[idx] = bfr(a - bff(ah));
        int n = idx >> 6, np = idx & 63;
        float w = ctab[(8 * np * (2 * n + 1)) & 2047];
        AcT[idx] = bfr(w * (np == 0 ? 0.125f : 0.17677669529663687f));
    }
}

__global__ void k_zero(unsigned* __restrict__ p, int n) {
    int i = blockIdx.x * 256 + threadIdx.x;
    if (i < n) p[i] = 0u;
}

// G = W1 x Ak^T via MFMA, output bf16 row-major (reshuffled by k_gf).
__global__ __launch_bounds__(256, 2) void k_gmm(const float* __restrict__ W1,
                                                const u16* __restrict__ Akh, const u16* __restrict__ Akl,
                                                u16* __restrict__ G) {
    __shared__ __align__(16) short Wh[128 * 40];
    __shared__ __align__(16) short Wl[128 * 40];
    __shared__ __align__(16) short Qh[128 * 40];
    __shared__ __align__(16) short Ql[128 * 40];
    const int p0 = blockIdx.y * 128, kc0 = blockIdx.x * 128;
    const int tid = threadIdx.x;
    const int lane = tid & 63, wave = tid >> 6;
    const int fr = lane & 15, qd = lane >> 4;
    const int mq = (wave >> 1) * 64, nq = (wave & 1) * 64;
    f32x4 acc[4][4];
#pragma unroll
    for (int i = 0; i < 4; ++i)
#pragma unroll
        for (int j = 0; j < 4; ++j) acc[i][j] = (f32x4){0.f, 0.f, 0.f, 0.f};
    const float* Pg = W1 + (long)p0 * 512;
    const u16* Qgh = Akh + (long)kc0 * 512;
    const u16* Qgl = Akl + (long)kc0 * 512;
    const int r0 = tid >> 2, q40 = (tid & 3) * 8;
    float4 pa4[2], pb4[2];
    s16x8 qsh[2], qsl[2];
#pragma unroll
    for (int j = 0; j < 2; ++j) {
        int r = r0 + j * 64;
        const float* src = &Pg[(long)r * 512 + q40];
        pa4[j] = *(const float4*)src;
        pb4[j] = *(const float4*)(src + 4);
        qsh[j] = *(const s16x8*)&Qgh[(long)r * 512 + q40];
        qsl[j] = *(const s16x8*)&Qgl[(long)r * 512 + q40];
    }
    for (int ch = 0; ch < 16; ++ch) {
        __syncthreads();
#pragma unroll
        for (int j = 0; j < 2; ++j) {
            int r = r0 + j * 64;
            float f[8] = {pa4[j].x, pa4[j].y, pa4[j].z, pa4[j].w,
                          pb4[j].x, pb4[j].y, pb4[j].z, pb4[j].w};
            s16x8 vh, vl;
#pragma unroll
            for (int q = 0; q < 8; ++q) {
                u16 h = bfr(f[q]);
                vh[q] = (short)h;
                vl[q] = (short)bfr(f[q] - bff(h));
            }
            *(s16x8*)&Wh[r * 40 + q40] = vh;
            *(s16x8*)&Wl[r * 40 + q40] = vl;
            *(s16x8*)&Qh[r * 40 + q40] = qsh[j];
            *(s16x8*)&Ql[r * 40 + q40] = qsl[j];
        }
        __syncthreads();
        if (ch < 15) {
            const int kn = (ch + 1) * 32;
#pragma unroll
            for (int j = 0; j < 2; ++j) {
                int r = r0 + j * 64;
                const float* src = &Pg[(long)r * 512 + kn + q40];
                pa4[j] = *(const float4*)src;
                pb4[j] = *(const float4*)(src + 4);
                qsh[j] = *(const s16x8*)&Qgh[(long)r * 512 + kn + q40];
                qsl[j] = *(const s16x8*)&Qgl[(long)r * 512 + kn + q40];
            }
        }
        s16x8 qfh[4], qfl[4];
#pragma unroll
        for (int j = 0; j < 4; ++j) {
            qfh[j] = *(const s16x8*)&Qh[(nq + 16 * j + fr) * 40 + qd * 8];
            qfl[j] = *(const s16x8*)&Ql[(nq + 16 * j + fr) * 40 + qd * 8];
        }
#pragma unroll
        for (int i = 0; i < 4; ++i) {
            s16x8 wh = *(const s16x8*)&Wh[(mq + 16 * i + fr) * 40 + qd * 8];
            s16x8 wl = *(const s16x8*)&Wl[(mq + 16 * i + fr) * 40 + qd * 8];
#pragma unroll
            for (int j = 0; j < 4; ++j) {
                acc[i][j] = MFMA(wh, qfh[j], acc[i][j]);
                acc[i][j] = MFMA(wh, qfl[j], acc[i][j]);
                acc[i][j] = MFMA(wl, qfh[j], acc[i][j]);
            }
        }
    }
#pragma unroll
    for (int i = 0; i < 4; ++i)
#pragma unroll
        for (int j = 0; j < 4; ++j) {
            int rowb = mq + 16 * i + qd * 4;
            int col = kc0 + nq + 16 * j + fr;
#pragma unroll
            for (int r = 0; r < 4; ++r)
                G[(long)(p0 + rowb + r) * 512 + col] = bfr(acc[i][j][r]);
        }
}

// reshuffle G (row-major) -> Gf (fragment-major): Gf[((br*16+ch)*8+of)*512+lane*8+q]
__global__ void k_gf(const u16* __restrict__ G, u16* __restrict__ Gf) {
    int fidx = blockIdx.x * 256 + threadIdx.x;   // 32768 units of 16B
    int lane = fidx & 63;
    int of = (fidx >> 6) & 7;
    int ch = (fidx >> 9) & 15;
    int br = fidx >> 13;
    int fr = lane & 15, qd = lane >> 4;
    s16x8 v = *(const s16x8*)&G[((long)(br * 128 + of * 16 + fr)) * 512 + ch * 32 + qd * 8];
    *(s16x8*)&Gf[(long)fidx * 8] = v;
}

// W2f fragment-major: [br][ch=36][of=8][lane=64][8]; W3f: [br][ch=4][of=8][lane][8]
__global__ void k_wprep(const float* __restrict__ W2, const float* __restrict__ W3,
                        u16* __restrict__ W2f, u16* __restrict__ W3f) {
    int idx = blockIdx.x * 256 + threadIdx.x;
    if (idx < 589824) {
        int q = idx & 7;
        int lane = (idx >> 3) & 63;
        int of = (idx >> 9) & 7;
        int rest = idx >> 12;
        int ch = rest % 36;
        int br = rest / 36;
        int o = of * 16 + (lane & 15);
        int t = ch >> 2;
        int ci = (ch & 3) * 32 + (lane >> 4) * 8 + q;
        W2f[idx] = bfr(W2[(((long)br * 128 + o) * 128 + ci) * 9 + t]);
    }
    if (idx < 65536) {
        int q = idx & 7;
        int lane = (idx >> 3) & 63;
        int of = (idx >> 9) & 7;
        int ch = (idx >> 12) & 3;
        int br = idx >> 14;
        int o = of * 16 + (lane & 15);
        int k = ch * 32 + (lane >> 4) * 8 + q;
        W3f[idx] = bfr(W3[((long)br * 128 + o) * 128 + k]);
    }
}

// ---------------- forward 2D DCT tile via MFMA ----------------
__global__ __launch_bounds__(256, 3) void k_tile_fwd(const float* __restrict__ in,
                                                     u16* __restrict__ out16,
                                                     const u16* __restrict__ Ach,
                                                     const u16* __restrict__ Acl) {
    __shared__ __align__(16) short Xb[64 * 72];
    __shared__ __align__(16) short Ah[64 * 72];
    __shared__ __align__(16) short Al[64 * 72];
    __shared__ __align__(16) short Uh[64 * 72];
    __shared__ __align__(16) short Ul[64 * 72];
    const int tid = threadIdx.x;
    const long tile = blockIdx.x;
    const float* __restrict__ src = in + tile * 4096;
    u16* __restrict__ dst = out16 + tile * 4096;
    {
        const int r = tid >> 2, q16 = (tid & 3) * 16;
        const float* s = &src[r * 64 + q16];
        float4 f0 = *(const float4*)s;
        float4 f1 = *(const float4*)(s + 4);
        float4 f2 = *(const float4*)(s + 8);
        float4 f3 = *(const float4*)(s + 12);
        s16x8 v0, v1;
        v0[0] = (short)bfr(f0.x); v0[1] = (short)bfr(f0.y);
        v0[2] = (short)bfr(f0.z); v0[3] = (short)bfr(f0.w);
        v0[4] = (short)bfr(f1.x); v0[5] = (short)bfr(f1.y);
        v0[6] = (short)bfr(f1.z); v0[7] = (short)bfr(f1.w);
        v1[0] = (short)bfr(f2.x); v1[1] = (short)bfr(f2.y);
        v1[2] = (short)bfr(f2.z); v1[3] = (short)bfr(f2.w);
        v1[4] = (short)bfr(f3.x); v1[5] = (short)bfr(f3.y);
        v1[6] = (short)bfr(f3.z); v1[7] = (short)bfr(f3.w);
        *(s16x8*)&Xb[r * 72 + q16] = v0;
        *(s16x8*)&Xb[r * 72 + q16 + 8] = v1;
        *(s16x8*)&Ah[r * 72 + q16] = *(const s16x8*)&Ach[r * 64 + q16];
        *(s16x8*)&Ah[r * 72 + q16 + 8] = *(const s16x8*)&Ach[r * 64 + q16 + 8];
        *(s16x8*)&Al[r * 72 + q16] = *(const s16x8*)&Acl[r * 64 + q16];
        *(s16x8*)&Al[r * 72 + q16 + 8] = *(const s16x8*)&Acl[r * 64 + q16 + 8];
    }
    __syncthreads();
    const int lane = tid & 63, wave = tid >> 6;
    const int fr = lane & 15, qd = lane >> 4;
    const int mq = (wave >> 1) * 32, nq = (wave & 1) * 32;
    f32x4 a1[2][2];
#pragma unroll
    for (int i = 0; i < 2; ++i)
#pragma unroll
        for (int j = 0; j < 2; ++j) a1[i][j] = (f32x4){0.f, 0.f, 0.f, 0.f};
#pragma unroll
    for (int ks = 0; ks < 2; ++ks) {
        const int k0 = ks * 32 + qd * 8;
        s16x8 xp[2];
#pragma unroll
        for (int i = 0; i < 2; ++i) xp[i] = *(const s16x8*)&Xb[(mq + 16 * i + fr) * 72 + k0];
#pragma unroll
        for (int j = 0; j < 2; ++j) {
            s16x8 qh = *(const s16x8*)&Ah[(nq + 16 * j + fr) * 72 + k0];
            s16x8 ql = *(const s16x8*)&Al[(nq + 16 * j + fr) * 72 + k0];
#pragma unroll
            for (int i = 0; i < 2; ++i) {
                a1[i][j] = MFMA(xp[i], qh, a1[i][j]);
                a1[i][j] = MFMA(xp[i], ql, a1[i][j]);
            }
        }
    }
#pragma unroll
    for (int i = 0; i < 2; ++i)
#pragma unroll
        for (int j = 0; j < 2; ++j) {
            int k1 = nq + 16 * j + fr;
            int mb = mq + 16 * i + qd * 4;
            ushort4 ph, pl;
            float v0 = a1[i][j][0], v1 = a1[i][j][1], v2 = a1[i][j][2], v3 = a1[i][j][3];
            ph.x = bfr(v0); ph.y = bfr(v1); ph.z = bfr(v2); ph.w = bfr(v3);
            pl.x = bfr(v0 - bff(ph.x)); pl.y = bfr(v1 - bff(ph.y));
            pl.z = bfr(v2 - bff(ph.z)); pl.w = bfr(v3 - bff(ph.w));
            *(ushort4*)&Uh[k1 * 72 + mb] = ph;
            *(ushort4*)&Ul[k1 * 72 + mb] = pl;
        }
    __syncthreads();
    f32x4 a2[2][2];
#pragma unroll
    for (int i = 0; i < 2; ++i)
#pragma unroll
        for (int j = 0; j < 2; ++j) a2[i][j] = (f32x4){0.f, 0.f, 0.f, 0.f};
#pragma unroll
    for (int ks = 0; ks < 2; ++ks) {
        const int k0 = ks * 32 + qd * 8;
        s16x8 uh[2], ul[2];
#pragma unroll
        for (int i = 0; i < 2; ++i) {
            uh[i] = *(const s16x8*)&Uh[(mq + 16 * i + fr) * 72 + k0];
            ul[i] = *(const s16x8*)&Ul[(mq + 16 * i + fr) * 72 + k0];
        }
#pragma unroll
        for (int j = 0; j < 2; ++j) {
            s16x8 qh = *(const s16x8*)&Ah[(nq + 16 * j + fr) * 72 + k0];
            s16x8 ql = *(const s16x8*)&Al[(nq + 16 * j + fr) * 72 + k0];
#pragma unroll
            for (int i = 0; i < 2; ++i) {
                a2[i][j] = MFMA(uh[i], qh, a2[i][j]);
                a2[i][j] = MFMA(uh[i], ql, a2[i][j]);
                a2[i][j] = MFMA(ul[i], qh, a2[i][j]);
            }
        }
    }
#pragma unroll
    for (int i = 0; i < 2; ++i)
#pragma unroll
        for (int j = 0; j < 2; ++j) {
            int k2 = nq + 16 * j + fr;
            int nb = mq + 16 * i + qd * 4;
            ushort4 pk;
            pk.x = bfr(a2[i][j][0]); pk.y = bfr(a2[i][j][1]);
            pk.z = bfr(a2[i][j][2]); pk.w = bfr(a2[i][j][3]);
            *(ushort4*)&dst[k2 * 64 + nb] = pk;
        }
}

// ---------------- transpose: t16 NCHW bf16 -> thi NHWC bf16 ----------------
__global__ __launch_bounds__(256) void k_tsplit(const u16* __restrict__ t16,
                                                u16* __restrict__ thi) {
    __shared__ float Ls[64][65];
    const int b = blockIdx.z, cg = blockIdx.y, pg = blockIdx.x;
    const int tid = threadIdx.x;
    const u16* src = t16 + ((long)b * 512 + cg * 64) * 4096 + pg * 64;
#pragma unroll
    for (int j = 0; j < 2; ++j) {
        int idx = tid + j * 256;
        int c = idx >> 3, p8 = (idx & 7) * 8;
        s16x8 v = *(const s16x8*)&src[(long)c * 4096 + p8];
#pragma unroll
        for (int q = 0; q < 8; ++q) Ls[c][p8 + q] = bff((u16)v[q]);
    }
    __syncthreads();
#pragma unroll
    for (int j = 0; j < 2; ++j) {
        int idx = tid + j * 256;
        int p = idx >> 3, c8 = idx & 7;
        s16x8 vh;
#pragma unroll
        for (int q = 0; q < 8; ++q) vh[q] = (short)bfr(Ls[c8 * 8 + q][p]);
        long addr = ((long)b * 4096 + pg * 64 + p) * 512 + cg * 64 + c8 * 8;
        *(s16x8*)&thi[addr] = vh;
    }
}

// ---------------- C-DCT GEMM + fused hist1 (LDS-staged Q; bf16 D output) ----------------
// hist1 over the 12-bit bf16-magnitude prefix ((u&0x7fff)>>3); packed u16-halves
// scheme: word w holds bin w (lo) and bin w+2048 (hi); per-block count<=16384.
__global__ __launch_bounds__(256, 4) void k_cgemm(const u16* __restrict__ thi,
                                                  const u16* __restrict__ Akh, const u16* __restrict__ Akl,
                                                  u16* __restrict__ D16, unsigned* __restrict__ g1) {
    __shared__ __align__(16) short Ph[128 * 40];
    __shared__ __align__(16) short Qh[128 * 40];
    __shared__ __align__(16) short Ql[128 * 40];
    __shared__ unsigned hh[2048];
    const int b = blockIdx.z;
    const int p0 = blockIdx.y * 128, kc0 = blockIdx.x * 128;
    const int tid = threadIdx.x;
    const int lane = tid & 63, wave = tid >> 6;
    const int fr = lane & 15, qd = lane >> 4;
    const int mq = (wave >> 1) * 64, nq = (wave & 1) * 64;
    for (int t = tid; t < 2048; t += 256) hh[t] = 0u;
    f32x4 acc[4][4];
#pragma unroll
    for (int i = 0; i < 4; ++i)
#pragma unroll
        for (int j = 0; j < 4; ++j) acc[i][j] = (f32x4){0.f, 0.f, 0.f, 0.f};
    const u16* Pgh = thi + ((long)b * 4096 + p0) * 512;
    const u16* Qgh = Akh + (long)kc0 * 512;
    const u16* Qgl = Akl + (long)kc0 * 512;
    const int r0 = tid >> 2, q40 = (tid & 3) * 8;
    s16x8 psh[2], qsh[2], qsl[2];
#pragma unroll
    for (int j = 0; j < 2; ++j) {
        int r = r0 + j * 64;
        psh[j] = *(const s16x8*)&Pgh[(long)r * 512 + q40];
        qsh[j] = *(const s16x8*)&Qgh[(long)r * 512 + q40];
        qsl[j] = *(const s16x8*)&Qgl[(long)r * 512 + q40];
    }
    for (int ch = 0; ch < 16; ++ch) {
        __syncthreads();
#pragma unroll
        for (int j = 0; j < 2; ++j) {
            int r = r0 + j * 64;
            *(s16x8*)&Ph[r * 40 + q40] = psh[j];
            *(s16x8*)&Qh[r * 40 + q40] = qsh[j];
            *(s16x8*)&Ql[r * 40 + q40] = qsl[j];
        }
        __syncthreads();
        if (ch < 15) {
            const int kn = (ch + 1) * 32;
#pragma unroll
            for (int j = 0; j < 2; ++j) {
                int r = r0 + j * 64;
                psh[j] = *(const s16x8*)&Pgh[(long)r * 512 + kn + q40];
                qsh[j] = *(const s16x8*)&Qgh[(long)r * 512 + kn + q40];
                qsl[j] = *(const s16x8*)&Qgl[(long)r * 512 + kn + q40];
            }
        }
        s16x8 qfh[4], qfl[4];
#pragma unroll
        for (int j = 0; j < 4; ++j) {
            qfh[j] = *(const s16x8*)&Qh[(nq + 16 * j + fr) * 40 + qd * 8];
            qfl[j] = *(const s16x8*)&Ql[(nq + 16 * j + fr) * 40 + qd * 8];
        }
#pragma unroll
        for (int i = 0; i < 4; ++i) {
            s16x8 ph = *(const s16x8*)&Ph[(mq + 16 * i + fr) * 40 + qd * 8];
#pragma unroll
            for (int j = 0; j < 4; ++j) {
                acc[i][j] = MFMA(ph, qfh[j], acc[i][j]);
                acc[i][j] = MFMA(ph, qfl[j], acc[i][j]);
            }
        }
    }
#pragma unroll
    for (int i = 0; i < 4; ++i)
#pragma unroll
        for (int j = 0; j < 4; ++j) {
            int rowb = mq + 16 * i + qd * 4;
            int col = kc0 + nq + 16 * j + fr;
#pragma unroll
            for (int r = 0; r < 4; ++r) {
                u16 pk = bfr(acc[i][j][r]);
                D16[((long)b * 4096 + p0 + rowb + r) * 512 + col] = pk;
                unsigned bin = (((unsigned)pk) & 0x7fffu) >> 3;
                atomicAdd(&hh[bin & 2047u], 1u << ((bin >> 11) << 4));
            }
        }
    __syncthreads();
    for (int t = tid; t < 2048; t += 256) {
        unsigned c = hh[t];
        unsigned lo = c & 0xffffu, hi = c >> 16;
        if (lo) atomicAdd(&g1[t], lo);
        if (hi) atomicAdd(&g1[t + 2048], hi);
    }
}

// ---------------- selection (12-bit prefix + 3-bit suffix, exact at bf16) ----------------
__global__ void k_scan1(const unsigned* __restrict__ hist, unsigned* __restrict__ sel) {
    __shared__ unsigned chunk[256];
    __shared__ unsigned above[256];
    const int t = threadIdx.x;
    unsigned s = 0;
#pragma unroll
    for (int j = 0; j < 16; ++j) s += hist[t * 16 + j];
    chunk[t] = s;
    __syncthreads();
    if (t == 0) {
        unsigned a = 0;
        for (int c = 255; c >= 0; --c) { above[c] = a; a += chunk[c]; }
    }
    __syncthreads();
    const unsigned kv[4] = {4194304u, 1048576u, 262144u, 65536u};
    unsigned run = above[t];
    for (int j = 15; j >= 0; --j) {
        unsigned bin = t * 16 + j;
        unsigned hb = hist[bin];
        unsigned Sab = run;
        run += hb;
#pragma unroll
        for (int i = 0; i < 4; ++i)
            if (run >= kv[i] && Sab < kv[i]) { sel[i] = bin; sel[4 + i] = kv[i] - Sab; }
    }
}

// compact candidates (bf16 patterns in selected prefix bins) into per-block slices
__global__ __launch_bounds__(256) void k_compact(const u16* __restrict__ D16,
                                                 const unsigned* __restrict__ sel,
                                                 unsigned* __restrict__ cand,
                                                 unsigned* __restrict__ cnt) {
    __shared__ unsigned lctr;
    if (threadIdx.x == 0) lctr = 0u;
    __syncthreads();
    const unsigned p0 = sel[0], p1 = sel[1], p2 = sel[2], p3 = sel[3];
    const int lane = threadIdx.x & 63;
    unsigned* slice = cand + (long)blockIdx.x * 4096;
    const long n8 = TOT / 8;
    for (long idx = (long)blockIdx.x * 256 + threadIdx.x; idx < n8; idx += (long)gridDim.x * 256) {
        s16x8 v = *(const s16x8*)&D16[idx * 8];
#pragma unroll
        for (int q = 0; q < 8; ++q) {
            unsigned u = (unsigned)(unsigned short)v[q];
            unsigned pre = (u & 0x7fffu) >> 3;
            bool m = (pre == p0) | (pre == p1) | (pre == p2) | (pre == p3);
            unsigned long long mask = __ballot(m);
            if (mask) {
                int leader = __ffsll((long long)mask) - 1;
                unsigned base = 0;
                if (lane == leader) base = atomicAdd(&lctr, (unsigned)__popcll(mask));
                base = (unsigned)__shfl((int)base, leader);
                if (m) {
                    unsigned pos = base + (unsigned)__popcll(mask & ((1ULL << lane) - 1ULL));
                    if (pos < 4096u) slice[pos] = u;
                }
            }
        }
    }
    __syncthreads();
    if (threadIdx.x == 0) cnt[blockIdx.x] = lctr < 4096u ? lctr : 4096u;
}

// suffix histogram: 3 low bits per selected prefix (32 counters total)
__global__ __launch_bounds__(256) void k_histsuf(const unsigned* __restrict__ cand,
                                                 const unsigned* __restrict__ cnt,
                                                 const unsigned* __restrict__ sel,
                                                 unsigned* __restrict__ h2) {
    __shared__ unsigned h[32];
    if (threadIdx.x < 32) h[threadIdx.x] = 0u;
    __syncthreads();
    const unsigned p0 = sel[0], p1 = sel[1], p2 = sel[2], p3 = sel[3];
    for (int s = 0; s < 8; ++s) {
        int slice = blockIdx.x * 8 + s;
        unsigned n = cnt[slice];
        const unsigned* L = cand + (long)slice * 4096;
        for (unsigned i = threadIdx.x; i < n; i += 256) {
            unsigned u = L[i] & 0x7fffu;
            unsigned pre = u >> 3, suf = u & 7u;
            if (pre == p0) atomicAdd(&h[suf], 1u);
            else if (pre == p1) atomicAdd(&h[8 + suf], 1u);
            else if (pre == p2) atomicAdd(&h[16 + suf], 1u);
            else if (pre == p3) atomicAdd(&h[24 + suf], 1u);
        }
    }
    __syncthreads();
    if (threadIdx.x < 32) {
        unsigned c = h[threadIdx.x];
        if (c) atomicAdd(&h2[threadIdx.x], c);
    }
}

// final threshold (bf16 magnitude pattern) per branch -> sel[8..11]
__global__ void k_scansuf(const unsigned* __restrict__ h2, unsigned* __restrict__ sel) {
    int t = threadIdx.x;
    if (t < 4) {
        unsigned r = sel[4 + t];
        unsigned run = 0, thr = 0;
        for (int s = 7; s >= 0; --s) {
            unsigned c = h2[t * 8 + s];
            if (run < r && run + c >= r) thr = (sel[t] << 3) | (unsigned)s;
            run += c;
        }
        sel[8 + t] = thr;
    }
}

// ---------------- conv1 fused with IDCT_C (bf16 D; integer threshold mask) ----------------
__global__ __launch_bounds__(256, 4) void k_conv1(const u16* __restrict__ D16, const u16* __restrict__ Gf,
                                                  const unsigned* __restrict__ sel, u16* __restrict__ h1pre) {
    __shared__ __align__(16) short Pt[128 * 40];
    const int b = blockIdx.z, br = blockIdx.y, p0 = blockIdx.x * 128;
    const int z2 = br * 8 + b;
    const unsigned thrp = sel[8 + br];
    const int tid = threadIdx.x;
    const int lane = tid & 63, wave = tid >> 6;
    const int fr = lane & 15, qd = lane >> 4;
    const int mq = (wave >> 1) * 64, nq = (wave & 1) * 64;
    f32x4 acc[4][4];
#pragma unroll
    for (int i = 0; i < 4; ++i)
#pragma unroll
        for (int j = 0; j < 4; ++j) acc[i][j] = (f32x4){0.f, 0.f, 0.f, 0.f};
    const u16* Pg = D16 + ((long)b * 4096 + p0) * 512;
    const int r0 = tid >> 2, q40 = (tid & 3) * 8;
    s16x8 dv[2];
#pragma unroll
    for (int j = 0; j < 2; ++j)
        dv[j] = *(const s16x8*)&Pg[(long)(r0 + j * 64) * 512 + q40];
    const long qb0 = (((long)br * 16) * 8 + (nq >> 4)) * 512 + (long)lane * 8;
    for (int ch = 0; ch < 16; ++ch) {
        const int k0 = ch * 32;
        __syncthreads();
#pragma unroll
        for (int j = 0; j < 2; ++j) {
            int r = r0 + j * 64;
            s16x8 m;
#pragma unroll
            for (int q = 0; q < 8; ++q) {
                unsigned mag = ((unsigned)(unsigned short)dv[j][q]) & 0x7fffu;
                m[q] = (mag >= thrp) ? dv[j][q] : (short)0;
            }
            *(s16x8*)&Pt[r * 40 + q40] = m;
        }
        __syncthreads();
        if (ch < 15) {
            const int kn = k0 + 32;
#pragma unroll
            for (int j = 0; j < 2; ++j)
                dv[j] = *(const s16x8*)&Pg[(long)(r0 + j * 64) * 512 + kn + q40];
        }
        const long qbase = qb0 + (long)ch * 4096;
        s16x8 qb[4];
#pragma unroll
        for (int j = 0; j < 4; ++j) qb[j] = *(const s16x8*)&Gf[qbase + (long)j * 512];
#pragma unroll
        for (int i = 0; i < 4; ++i) {
            s16x8 pa = *(const s16x8*)&Pt[(mq + 16 * i + fr) * 40 + qd * 8];
#pragma unroll
            for (int j = 0; j < 4; ++j) acc[i][j] = MFMA(pa, qb[j], acc[i][j]);
        }
    }
#pragma unroll
    for (int i = 0; i < 4; ++i)
#pragma unroll
        for (int j = 0; j < 4; ++j) {
            int rowb = p0 + mq + 16 * i + qd * 4;
            int o = nq + 16 * j + fr;
            ushort4 pk;
            pk.x = bfr(acc[i][j][0]); pk.y = bfr(acc[i][j][1]);
            pk.z = bfr(acc[i][j][2]); pk.w = bfr(acc[i][j][3]);
            *(ushort4*)&h1pre[((long)z2 * 128 + o) * 4096 + rowb] = pk;
        }
}

// ---------------- IDCT passes ----------------
__global__ __launch_bounds__(256, 4) void k_idct1(const u16* __restrict__ h1pre, const u16* __restrict__ AcT,
                                                  u16* __restrict__ X2) {
    __shared__ __align__(16) short Pt[128 * 72];
    __shared__ __align__(16) short Qt[64 * 72];
    const int b = blockIdx.z, br = blockIdx.y, m0 = blockIdx.x * 128;
    const int z2 = br * 8 + b;
    const int tid = threadIdx.x;
    const int lane = tid & 63, wave = tid >> 6;
    const int fr = lane & 15, qd = lane >> 4;
    const int mq = wave * 32;
    const u16* Pg = h1pre + (long)z2 * 524288 + (long)m0 * 64;
    f32x4 acc[2][4];
#pragma unroll
    for (int i = 0; i < 2; ++i)
#pragma unroll
        for (int j = 0; j < 4; ++j) acc[i][j] = (f32x4){0.f, 0.f, 0.f, 0.f};
#pragma unroll
    for (int j = 0; j < 4; ++j) {
        int idx = tid + j * 256;
        int r = idx >> 3, q8 = (idx & 7) * 8;
        *(s16x8*)&Pt[r * 72 + q8] = *(const s16x8*)&Pg[(long)r * 64 + q8];
    }
#pragma unroll
    for (int j = 0; j < 2; ++j) {
        int idx = tid + j * 256;
        int r = idx >> 3, q8 = (idx & 7) * 8;
        *(s16x8*)&Qt[r * 72 + q8] = *(const s16x8*)&AcT[(long)r * 64 + q8];
    }
    __syncthreads();
#pragma unroll
    for (int ks = 0; ks < 2; ++ks) {
        s16x8 pa[2], qb[4];
#pragma unroll
        for (int i = 0; i < 2; ++i) pa[i] = *(const s16x8*)&Pt[(mq + 16 * i + fr) * 72 + ks * 32 + qd * 8];
#pragma unroll
        for (int j = 0; j < 4; ++j) qb[j] = *(const s16x8*)&Qt[(16 * j + fr) * 72 + ks * 32 + qd * 8];
#pragma unroll
        for (int i = 0; i < 2; ++i)
#pragma unroll
            for (int j = 0; j < 4; ++j) acc[i][j] = MFMA(pa[i], qb[j], acc[i][j]);
    }
#pragma unroll
    for (int i = 0; i < 2; ++i)
#pragma unroll
        for (int j = 0; j < 4; ++j) {
            int Rb = m0 + mq + 16 * i + qd * 4;
            int o = Rb >> 6, y = Rb & 63;
            int xo = 16 * j + fr;
            ushort4 pk;
            pk.x = bfr(acc[i][j][0]); pk.y = bfr(acc[i][j][1]);
            pk.z = bfr(acc[i][j][2]); pk.w = bfr(acc[i][j][3]);
            *(ushort4*)&X2[(long)z2 * 524288 + ((long)xo * 128 + o) * 64 + y] = pk;
        }
}

__global__ __launch_bounds__(256, 4) void k_idct2(const u16* __restrict__ X2, const u16* __restrict__ AcT,
                                                  const float* __restrict__ b1, u16* __restrict__ h1) {
    __shared__ __align__(16) short Pt[128 * 72];
    __shared__ __align__(16) short Qt[64 * 72];
    const int b = blockIdx.z, br = blockIdx.y, m0 = blockIdx.x * 128;
    const int z2 = br * 8 + b;
    const int tid = threadIdx.x;
    const int lane = tid & 63, wave = tid >> 6;
    const int fr = lane & 15, qd = lane >> 4;
    const int mq = wave * 32;
    const u16* Pg = X2 + (long)z2 * 524288 + (long)m0 * 64;
    f32x4 acc[2][4];
#pragma unroll
    for (int i = 0; i < 2; ++i)
#pragma unroll
        for (int j = 0; j < 4; ++j) acc[i][j] = (f32x4){0.f, 0.f, 0.f, 0.f};
#pragma unroll
    for (int j = 0; j < 4; ++j) {
        int idx = tid + j * 256;
        int r = idx >> 3, q8 = (idx & 7) * 8;
        *(s16x8*)&Pt[r * 72 + q8] = *(const s16x8*)&Pg[(long)r * 64 + q8];
    }
#pragma unroll
    for (int j = 0; j < 2; ++j) {
        int idx = tid + j * 256;
        int r = idx >> 3, q8 = (idx & 7) * 8;
        *(s16x8*)&Qt[r * 72 + q8] = *(const s16x8*)&AcT[(long)r * 64 + q8];
    }
    __syncthreads();
#pragma unroll
    for (int ks = 0; ks < 2; ++ks) {
        s16x8 pa[2], qb[4];
#pragma unroll
        for (int i = 0; i < 2; ++i) pa[i] = *(const s16x8*)&Pt[(mq + 16 * i + fr) * 72 + ks * 32 + qd * 8];
#pragma unroll
        for (int j = 0; j < 4; ++j) qb[j] = *(const s16x8*)&Qt[(16 * j + fr) * 72 + ks * 32 + qd * 8];
#pragma unroll
        for (int i = 0; i < 2; ++i)
#pragma unroll
            for (int j = 0; j < 4; ++j) acc[i][j] = MFMA(pa[i], qb[j], acc[i][j]);
    }
#pragma unroll
    for (int i = 0; i < 2; ++i)
#pragma unroll
        for (int j = 0; j < 4; ++j) {
            int Rb = m0 + mq + 16 * i + qd * 4;
            int xo = Rb >> 7, o = Rb & 127;
            int yo = 16 * j + fr;
            ushort4 pk;
            const float* bg = b1 + br * 128 + o;
            pk.x = bfr(fmaxf(acc[i][j][0] + bg[0], 0.f));
            pk.y = bfr(fmaxf(acc[i][j][1] + bg[1], 0.f));
            pk.z = bfr(fmaxf(acc[i][j][2] + bg[2], 0.f));
            pk.w = bfr(fmaxf(acc[i][j][3] + bg[3], 0.f));
            *(ushort4*)&h1[(long)z2 * 524288 + ((long)yo * 64 + xo) * 128 + o] = pk;
        }
}

// ---------------- conv2: implicit GEMM (W direct from fragment-major global) ----------------
__global__ __launch_bounds__(256, 4) void k_conv2(const u16* __restrict__ h1, const u16* __restrict__ W2f,
                                                  const float* __restrict__ b2, u16* __restrict__ h2) {
    __shared__ __align__(16) short Pt[128 * 40];
    const int b = blockIdx.z, br = blockIdx.y;
    const int bx = blockIdx.x;
    const int y0 = ((bx & 7) * 4 + (bx >> 3)) * 2;   // XCD-aware y-tile swizzle
    const int z2 = br * 8 + b;
    const int tid = threadIdx.x;
    const int lane = tid & 63, wave = tid >> 6;
    const int fr = lane & 15, qd = lane >> 4;
    const int mq = (wave >> 1) * 64, nq = (wave & 1) * 64;
    f32x4 acc[4][4];
#pragma unroll
    for (int i = 0; i < 4; ++i)
#pragma unroll
        for (int j = 0; j < 4; ++j) acc[i][j] = (f32x4){0.f, 0.f, 0.f, 0.f};
    const u16* hb = h1 + (long)z2 * 524288;
    const int r0 = tid >> 2, q40 = (tid & 3) * 8;
    s16x8 preg[2];
    auto loadP = [&](int ch) {
        const int t9 = ch >> 2, ci0 = (ch & 3) * 32;
        const int ky = t9 / 3, kx = t9 - 3 * ky;
        const int dy = 2 * ky - 2, dx = 2 * kx - 2;
#pragma unroll
        for (int j = 0; j < 2; ++j) {
            int r = r0 + j * 64;
            int ry = r >> 6, xx = r & 63;
            int ysrc = y0 + ry + dy, xsrc = xx + dx;
            s16x8 v = {0, 0, 0, 0, 0, 0, 0, 0};
            if ((unsigned)ysrc < 64u && (unsigned)xsrc < 64u)
                v = *(const s16x8*)&hb[((long)ysrc * 64 + xsrc) * 128 + ci0 + q40];
            preg[j] = v;
        }
    };
    loadP(0);
    const long qb0 = (((long)br * 36) * 8 + (nq >> 4)) * 512 + (long)lane * 8;
    for (int ch = 0; ch < 36; ++ch) {
        __syncthreads();
#pragma unroll
        for (int j = 0; j < 2; ++j)
            *(s16x8*)&Pt[(r0 + j * 64) * 40 + q40] = preg[j];
        __syncthreads();
        if (ch < 35) loadP(ch + 1);
        const long qbase = qb0 + (long)ch * 4096;
        s16x8 qb[4];
#pragma unroll
        for (int j = 0; j < 4; ++j) qb[j] = *(const s16x8*)&W2f[qbase + (long)j * 512];
#pragma unroll
        for (int i = 0; i < 4; ++i) {
            s16x8 pa = *(const s16x8*)&Pt[(mq + 16 * i + fr) * 40 + qd * 8];
#pragma unroll
            for (int j = 0; j < 4; ++j) acc[i][j] = MFMA(pa, qb[j], acc[i][j]);
        }
    }
#pragma unroll
    for (int i = 0; i < 4; ++i)
#pragma unroll
        for (int j = 0; j < 4; ++j) {
            int rowb = mq + 16 * i + qd * 4;
            int o = nq + 16 * j + fr;
            float bb = b2[br * 128 + o];
#pragma unroll
            for (int r = 0; r < 4; ++r) {
                float v = fmaxf(acc[i][j][r] + bb, 0.f);
                h2[(long)z2 * 524288 + ((long)y0 * 64 + rowb + r) * 128 + o] = bfr(v);
            }
        }
}

// ---------------- conv3: writes bf16 logits in [b][m][c][n] layout ----------------
__global__ __launch_bounds__(256, 4) void k_conv3(const u16* __restrict__ h2, const u16* __restrict__ W3f,
                                                  const float* __restrict__ b3, u16* __restrict__ lgn) {
    __shared__ __align__(16) short buf[18432];
    short* Pt = buf;
    const int b = blockIdx.z, br = blockIdx.y, p0 = blockIdx.x * 128;
    const int z2 = br * 8 + b;
    const int m0 = blockIdx.x * 2;
    const int tid = threadIdx.x;
    const int lane = tid & 63, wave = tid >> 6;
    const int fr = lane & 15, qd = lane >> 4;
    const int mq = (wave >> 1) * 64, nq = (wave & 1) * 64;
    f32x4 acc[4][4];
#pragma unroll
    for (int i = 0; i < 4; ++i)
#pragma unroll
        for (int j = 0; j < 4; ++j) acc[i][j] = (f32x4){0.f, 0.f, 0.f, 0.f};
    const u16* Pg = h2 + (long)z2 * 524288 + (long)p0 * 128;
    const long qb0 = (((long)br * 4) * 8 + (nq >> 4)) * 512 + (long)lane * 8;
    for (int ch = 0; ch < 4; ++ch) {
        const int k0 = ch * 32;
        __syncthreads();
#pragma unroll
        for (int j = 0; j < 2; ++j) {
            int idx = tid + j * 256;
            int r = idx >> 2, q4 = (idx & 3) * 8;
            *(s16x8*)&Pt[r * 40 + q4] = *(const s16x8*)&Pg[(long)r * 128 + k0 + q4];
        }
        __syncthreads();
        const long qbase = qb0 + (long)ch * 4096;
        s16x8 qb[4];
#pragma unroll
        for (int j = 0; j < 4; ++j) qb[j] = *(const s16x8*)&W3f[qbase + (long)j * 512];
#pragma unroll
        for (int i = 0; i < 4; ++i) {
            s16x8 pa = *(const s16x8*)&Pt[(mq + 16 * i + fr) * 40 + qd * 8];
#pragma unroll
            for (int j = 0; j < 4; ++j) acc[i][j] = MFMA(pa, qb[j], acc[i][j]);
        }
    }
    __syncthreads();
#pragma unroll
    for (int i = 0; i < 4; ++i)
#pragma unroll
        for (int j = 0; j < 4; ++j) {
            int l = mq + 16 * i + qd * 4;
            int mrow = l >> 6, nn = l & 63;
            int o = nq + 16 * j + fr;
            float bb = b3[br * 128 + o];
            ushort4 pk;
            pk.x = bfr(fmaxf(acc[i][j][0] + bb, 0.f));
            pk.y = bfr(fmaxf(acc[i][j][1] + bb, 0.f));
            pk.z = bfr(fmaxf(acc[i][j][2] + bb, 0.f));
            pk.w = bfr(fmaxf(acc[i][j][3] + bb, 0.f));
            *(ushort4*)&buf[mrow * 9216 + o * 72 + nn] = pk;
        }
    __syncthreads();
#pragma unroll
    for (int t = 0; t < 16; ++t) {
        int u = tid + t * 256;
        int mrow = u >> 11;
        int rem = u & 2047;
        int cl = rem >> 4, n4 = (rem & 15) << 2;
        ushort4 v = *(const ushort4*)&buf[mrow * 9216 + cl * 72 + n4];
        long dst = (((long)b * 64 + m0 + mrow) * 512 + br * 128 + cl) * 64 + n4;
        *(ushort4*)&lgn[dst] = v;
    }
}

// ---------------- softmax gating + residual (lgn [b][m][c][n], vectorized) ----------------
__global__ __launch_bounds__(256) void k_final(const float* __restrict__ x, const u16* __restrict__ lgn,
                                               float* __restrict__ out) {
    const int b = blockIdx.y, m = blockIdx.x;
    const int tid = threadIdx.x;
    const int csub = tid >> 3, oct = tid & 7;
    const u16* L = lgn + ((long)b * 64 + m) * 512 * 64;
    __shared__ float redm[32][64];
    __shared__ float reds[32][64];
    __shared__ float Mf[64], Sf[64];
    float mx[8], sm[8];
#pragma unroll
    for (int q = 0; q < 8; ++q) { mx[q] = -1e30f; sm[q] = 0.f; }
#pragma unroll 4
    for (int k = 0; k < 16; ++k) {
        int c = csub * 16 + k;
        s16x8 v8 = *(const s16x8*)&L[c * 64 + oct * 8];
#pragma unroll
        for (int q = 0; q < 8; ++q) {
            float v = bff((u16)v8[q]);
            float mn = fmaxf(mx[q], v);
            sm[q] = sm[q] * __expf(mx[q] - mn) + __expf(v - mn);
            mx[q] = mn;
        }
    }
#pragma unroll
    for (int q = 0; q < 8; ++q) {
        redm[csub][oct * 8 + q] = mx[q];
        reds[csub][oct * 8 + q] = sm[q];
    }
    __syncthreads();
    if (tid < 64) {
        float M = -1e30f;
#pragma unroll 8
        for (int g = 0; g < 32; ++g) M = fmaxf(M, redm[g][tid]);
        float S = 0.f;
#pragma unroll 8
        for (int g = 0; g < 32; ++g) S += reds[g][tid] * __expf(redm[g][tid] - M);
        Mf[tid] = M;
        Sf[tid] = 1.0f / S;
    }
    __syncthreads();
    float Mv[8], Iv[8];
#pragma unroll
    for (int q = 0; q < 8; ++q) { Mv[q] = Mf[oct * 8 + q]; Iv[q] = Sf[oct * 8 + q]; }
    const long xb = (long)b * 512 * 4096 + m * 64 + oct * 8;
#pragma unroll 4
    for (int k = 0; k < 16; ++k) {
        int c = csub * 16 + k;
        s16x8 v8 = *(const s16x8*)&L[c * 64 + oct * 8];
        long a = xb + (long)c * 4096;
        float4 x0 = *(const float4*)&x[a];
        float4 x1 = *(const float4*)&x[a + 4];
        float xf[8] = {x0.x, x0.y, x0.z, x0.w, x1.x, x1.y, x1.z, x1.w};
        float r[8];
#pragma unroll
        for (int q = 0; q < 8; ++q) {
            float w = __expf(bff((u16)v8[q]) - Mv[q]) * Iv[q];
            r[q] = xf[q] * w + xf[q];
        }
        *(float4*)&out[a] = make_float4(r[0], r[1], r[2], r[3]);
        *(float4*)&out[a + 4] = make_float4(r[4], r[5], r[6], r[7]);
    }
}

// ---------------------------------------------------------------------------
extern "C" void kernel_launch(void* const* d_in, const int* in_sizes, int n_in,
                              void* d_out, int out_size, void* d_ws, size_t ws_size,
                              hipStream_t stream) {
    (void)in_sizes; (void)n_in; (void)out_size; (void)ws_size;
    const float* x  = (const float*)d_in[0];
    const float* W1 = (const float*)d_in[1];
    const float* b1 = (const float*)d_in[2];
    const float* W2 = (const float*)d_in[3];
    const float* b2 = (const float*)d_in[4];
    const float* W3 = (const float*)d_in[5];
    const float* b3 = (const float*)d_in[6];
    float* out = (float*)d_out;
    float* ws = (float*)d_ws;

    u16*   t16  = (u16*)(ws + OFF_T);
    unsigned* cand = (unsigned*)(ws + OFF_CAND);
    unsigned* cnt  = (unsigned*)(ws + OFF_CNT);
    u16*   h1pre= (u16*)(ws + OFF_H1P);
    u16*   lgn  = (u16*)(ws + OFF_H1P);
    u16*   X2   = (u16*)(ws + OFF_X2);
    u16*   thi  = (u16*)(ws + OFF_THI);
    u16*   h1   = (u16*)(ws + OFF_H1);
    u16*   Gf   = (u16*)(ws + OFF_GF);
    u16*   D16  = (u16*)(ws + OFF_D);
    float* ctab = ws + OFF_D;
    u16*   h2   = (u16*)(ws + OFF_H2);
    u16*   Akh  = (u16*)(ws + OFF_AKH);
    u16*   Akl  = (u16*)(ws + OFF_AKL);
    u16*   AcT  = (u16*)(ws + OFF_ACT);
    u16*   Gb   = (u16*)(ws + OFF_GBF);
    u16*   W2f  = (u16*)(ws + OFF_W2A);
    u16*   W3f  = (u16*)(ws + OFF_W3B);
    unsigned* hist1 = (unsigned*)(ws + OFF_HIST);
    unsigned* h2r2  = (unsigned*)(ws + OFF_HIST) + 4096;
    unsigned* sel   = (unsigned*)(ws + OFF_SEL);
    u16*   Ach  = (u16*)(ws + OFF_ACH);
    u16*   Acl  = (u16*)(ws + OFF_ACL);

    k_ctab<<<8, 256, 0, stream>>>(ctab);
    k_build_mats<<<1024, 256, 0, stream>>>(ctab, Akh, Akl, AcT, Ach, Acl);
    k_zero<<<17, 256, 0, stream>>>(hist1, 4128);   // hist1[4096] + h2r2[32]
    k_gmm<<<dim3(4, 4), 256, 0, stream>>>(W1, Akh, Akl, Gb);
    k_gf<<<128, 256, 0, stream>>>(Gb, Gf);
    k_wprep<<<2304, 256, 0, stream>>>(W2, W3, W2f, W3f);

    // forward spatial DCT via MFMA -> t16 NCHW bf16
    k_tile_fwd<<<4096, 256, 0, stream>>>(x, t16, Ach, Acl);
    // transpose to NHWC bf16
    k_tsplit<<<dim3(64, 8, 8), 256, 0, stream>>>(t16, thi);
    // C-axis DCT via bf16 MFMA -> D16 bf16 NHWC (+ fused hist1)
    k_cgemm<<<dim3(4, 32, 8), 256, 0, stream>>>(thi, Akh, Akl, D16, hist1);

    // exact top-k thresholds at bf16 granularity
    k_scan1<<<1, 256, 0, stream>>>(hist1, sel);
    k_compact<<<2048, 256, 0, stream>>>(D16, sel, cand, cnt);
    k_histsuf<<<256, 256, 0, stream>>>(cand, cnt, sel, h2r2);
    k_scansuf<<<1, 64, 0, stream>>>(h2r2, sel);

    // branches (all 4 concurrent via grid.y)
    k_conv1<<<dim3(32, 4, 8), 256, 0, stream>>>(D16, Gf, sel, h1pre);
    k_idct1<<<dim3(64, 4, 8), 256, 0, stream>>>(h1pre, AcT, X2);
    k_idct2<<<dim3(64, 4, 8), 256, 0, stream>>>(X2, AcT, b1, h1);
    k_conv2<<<dim3(32, 4, 8), 256, 0, stream>>>(h1, W2f, b2, h2);
    k_conv3<<<dim3(32, 4, 8), 256, 0, stream>>>(h2, W3f, b3, lgn);

    k_final<<<dim3(64, 8), 256, 0, stream>>>(x, lgn, out);
}